// Round 3
// baseline (4788.931 us; speedup 1.0000x reference)
//
#include <hip/hip_runtime.h>
#include <hip/hip_bf16.h>
#include <stdint.h>

// Decoder: 2-layer LSTM + Luong attention. input_feed=0 => attention deferred
// post-loop. R3: the whole 64-step recurrence runs in ONE persistent kernel
// (128 blocks, hand grid barrier, c-state in registers, h hi/lo split,
// operands streamed from L2 with no LDS staging). Pre/post GEMMs as R2.

typedef __bf16 bf16_t;
typedef __bf16 bf16x8 __attribute__((ext_vector_type(8)));
typedef __bf16 bf16x4 __attribute__((ext_vector_type(4)));
typedef float f32x4 __attribute__((ext_vector_type(4)));

#define AS1 __attribute__((address_space(1)))
#define AS3 __attribute__((address_space(3)))

__device__ __forceinline__ void gll16(const bf16_t* g, bf16_t* l) {
  __builtin_amdgcn_global_load_lds((const AS1 void*)g, (AS3 void*)l, 16, 0, 0);
}

__device__ __forceinline__ float sigm(float x){ return 1.f/(1.f+expf(-x)); }

#define MFMA16(acc, a, b) acc = __builtin_amdgcn_mfma_f32_16x16x32_bf16(a, b, acc, 0,0,0)

// ---------------- prep kernels ----------------
__global__ void f2b(const float* __restrict__ in, bf16_t* __restrict__ outp, int n){
  int i = (blockIdx.x*256 + threadIdx.x)*4;
  if (i >= n) return;
  float4 v = *(const float4*)(in + i);
  bf16x4 o; o[0]=(bf16_t)v.x; o[1]=(bf16_t)v.y; o[2]=(bf16_t)v.z; o[3]=(bf16_t)v.w;
  *(bf16x4*)(outp + i) = o;
}

__global__ void f2b_pair(const float* __restrict__ in, bf16_t* __restrict__ oh,
                         bf16_t* __restrict__ ol, int n){
  int i = (blockIdx.x*256 + threadIdx.x)*4;
  if (i >= n) return;
  float4 v = *(const float4*)(in + i);
  float vv[4] = {v.x, v.y, v.z, v.w};
  bf16x4 h, l;
  #pragma unroll
  for (int j=0;j<4;j++){ h[j]=(bf16_t)vv[j]; l[j]=(bf16_t)(vv[j]-(float)h[j]); }
  *(bf16x4*)(oh + i) = h;
  *(bf16x4*)(ol + i) = l;
}

__global__ void bias_combine(const float* __restrict__ a, const float* __restrict__ b,
                             float* __restrict__ o, int n){
  int i = blockIdx.x*256 + threadIdx.x;
  if (i < n) o[i] = a[i] + b[i];
}

__global__ void embed_gather(const int* __restrict__ tokp, const float* __restrict__ embW,
                             bf16_t* __restrict__ xe){
  int m = blockIdx.x;
  int tokv = tokp[m];
  const float* src = embW + (size_t)tokv*1024 + threadIdx.x*4;
  float4 v = *(const float4*)src;
  bf16x4 o; o[0]=(bf16_t)v.x; o[1]=(bf16_t)v.y; o[2]=(bf16_t)v.z; o[3]=(bf16_t)v.w;
  *(bf16x4*)(xe + (size_t)m*1024 + threadIdx.x*4) = o;
}

// winT[e,d] = split(Win[d,e])
__global__ void transWin(const float* __restrict__ in, bf16_t* __restrict__ oh,
                         bf16_t* __restrict__ ol){
  __shared__ float t[32][33];
  int bi = blockIdx.x & 31, bj = blockIdx.x >> 5;
  int tx = threadIdx.x & 31, ty = threadIdx.x >> 5;  // 32 x 8
  #pragma unroll
  for (int i=0;i<4;i++){
    int d = bi*32 + ty + i*8, e = bj*32 + tx;
    t[ty+i*8][tx] = in[(size_t)d*1024 + e];
  }
  __syncthreads();
  #pragma unroll
  for (int i=0;i<4;i++){
    int e = bj*32 + ty + i*8, d = bi*32 + tx;
    float v = t[tx][ty+i*8];
    bf16_t h = (bf16_t)v;
    oh[(size_t)e*1024 + d] = h;
    ol[(size_t)e*1024 + d] = (bf16_t)(v - (float)h);
  }
}

// ---------------- plain bf16 GEMM (x0g): C = A@B^T + bias, out bf16 ----------------
__global__ __launch_bounds__(256) void gemm_bt(
    const bf16_t* __restrict__ A, const bf16_t* __restrict__ Bm,
    const float* __restrict__ bias, bf16_t* __restrict__ Cout,
    int M, int N, int K, int nTN)
{
  __shared__ bf16_t sA[128*64];
  __shared__ bf16_t sB[128*64];
  int tid = threadIdx.x, lane = tid & 63, w = tid >> 6;
  int tm = blockIdx.x / nTN, tn = blockIdx.x % nTN;
  int row0 = tm*128, col0 = tn*128;
  int wr = w >> 1, wcc = w & 1;
  f32x4 acc[4][4] = {};
  for (int kt = 0; kt < K; kt += 64) {
    __syncthreads();
    #pragma unroll
    for (int i=0;i<4;i++){
      int c = i*256 + tid;
      int r = c >> 3, kk = (c & 7) << 3;
      gll16(A  + (size_t)(row0+r)*K + kt + kk, sA + (size_t)(i*256 + w*64)*8);
      gll16(Bm + (size_t)(col0+r)*K + kt + kk, sB + (size_t)(i*256 + w*64)*8);
    }
    __syncthreads();
    #pragma unroll
    for (int kk=0;kk<64;kk+=32){
      bf16x8 av[4], bv[4];
      #pragma unroll
      for (int m=0;m<4;m++) av[m] = *(const bf16x8*)(sA + (wr*64 + m*16 + (lane&15))*64 + kk + ((lane>>4)<<3));
      #pragma unroll
      for (int n=0;n<4;n++) bv[n] = *(const bf16x8*)(sB + (wcc*64 + n*16 + (lane&15))*64 + kk + ((lane>>4)<<3));
      #pragma unroll
      for (int m=0;m<4;m++)
        #pragma unroll
        for (int n=0;n<4;n++)
          acc[m][n] = __builtin_amdgcn_mfma_f32_16x16x32_bf16(av[m], bv[n], acc[m][n], 0,0,0);
    }
  }
  #pragma unroll
  for (int n=0;n<4;n++){
    int cn = col0 + wcc*64 + n*16 + (lane & 15);
    float bvv = bias[cn];
    #pragma unroll
    for (int m=0;m<4;m++){
      int rm = row0 + wr*64 + m*16 + ((lane>>4)<<2);
      #pragma unroll
      for (int r=0;r<4;r++)
        Cout[(size_t)(rm+r)*N + cn] = (bf16_t)(acc[m][n][r] + bvv);
    }
  }
}

// ---------------- split GEMM: hi/lo A (two K-parts) x hi/lo B, 3 combos ----------------
template<int ACT_TANH, int OUT_PAIR>
__global__ __launch_bounds__(256) void gemm_split(
    const bf16_t* __restrict__ Ah1, const bf16_t* __restrict__ Al1,
    const bf16_t* __restrict__ Ah2, const bf16_t* __restrict__ Al2, int K1,
    const bf16_t* __restrict__ Bh, const bf16_t* __restrict__ Bl,
    float* __restrict__ Cf, bf16_t* __restrict__ Ch, bf16_t* __restrict__ Cl,
    int M, int N, int K, int nTN)
{
  __shared__ bf16_t sAh[128*64], sAl[128*64], sBh[128*64], sBl[128*64];
  int tid = threadIdx.x, lane = tid & 63, w = tid >> 6;
  int tm = blockIdx.x / nTN, tn = blockIdx.x % nTN;
  int row0 = tm*128, col0 = tn*128;
  int wr = w >> 1, wcc = w & 1;
  f32x4 acc[4][4] = {};
  for (int kt = 0; kt < K; kt += 64) {
    const bf16_t *Ah, *Al; int kl;
    if (kt < K1){ Ah=Ah1; Al=Al1; kl=kt; } else { Ah=Ah2; Al=Al2; kl=kt-K1; }
    __syncthreads();
    #pragma unroll
    for (int i=0;i<4;i++){
      int c = i*256 + tid;
      int r = c >> 3, kk = (c & 7) << 3;
      gll16(Ah + (size_t)(row0+r)*K1 + kl + kk, sAh + (size_t)(i*256 + w*64)*8);
      gll16(Al + (size_t)(row0+r)*K1 + kl + kk, sAl + (size_t)(i*256 + w*64)*8);
      gll16(Bh + (size_t)(col0+r)*K + kt + kk, sBh + (size_t)(i*256 + w*64)*8);
      gll16(Bl + (size_t)(col0+r)*K + kt + kk, sBl + (size_t)(i*256 + w*64)*8);
    }
    __syncthreads();
    #pragma unroll
    for (int kk=0;kk<64;kk+=32){
      bf16x8 avh[4], avl[4], bvh[4], bvl[4];
      #pragma unroll
      for (int m=0;m<4;m++){
        int off = (wr*64 + m*16 + (lane&15))*64 + kk + ((lane>>4)<<3);
        avh[m] = *(const bf16x8*)(sAh + off);
        avl[m] = *(const bf16x8*)(sAl + off);
      }
      #pragma unroll
      for (int n=0;n<4;n++){
        int off = (wcc*64 + n*16 + (lane&15))*64 + kk + ((lane>>4)<<3);
        bvh[n] = *(const bf16x8*)(sBh + off);
        bvl[n] = *(const bf16x8*)(sBl + off);
      }
      #pragma unroll
      for (int m=0;m<4;m++)
        #pragma unroll
        for (int n=0;n<4;n++){
          acc[m][n] = __builtin_amdgcn_mfma_f32_16x16x32_bf16(avh[m], bvh[n], acc[m][n], 0,0,0);
          acc[m][n] = __builtin_amdgcn_mfma_f32_16x16x32_bf16(avl[m], bvh[n], acc[m][n], 0,0,0);
          acc[m][n] = __builtin_amdgcn_mfma_f32_16x16x32_bf16(avh[m], bvl[n], acc[m][n], 0,0,0);
        }
    }
  }
  #pragma unroll
  for (int n=0;n<4;n++){
    int cn = col0 + wcc*64 + n*16 + (lane & 15);
    #pragma unroll
    for (int m=0;m<4;m++){
      int rm = row0 + wr*64 + m*16 + ((lane>>4)<<2);
      #pragma unroll
      for (int r=0;r<4;r++){
        float v = acc[m][n][r];
        if (ACT_TANH) v = tanhf(v);
        if (OUT_PAIR){
          bf16_t h = (bf16_t)v;
          Ch[(size_t)(rm+r)*N + cn] = h;
          Cl[(size_t)(rm+r)*N + cn] = (bf16_t)(v - (float)h);
        } else {
          Cf[(size_t)(rm+r)*N + cn] = v;
        }
      }
    }
  }
}

// ---------------- persistent LSTM loop kernel ----------------
// 128 blocks x 256 thr. Block owns 8 hidden cols (32 gate rows) of both layers.
// Phase p: lstm0 step p (p<64) and lstm1 step p-1 (p>=1) share h0[p-1] A-frags.
// c-state in registers. h hi/lo split. Grid barrier: monotonic atomic counter.
#define NBLK 128

__device__ __forceinline__ void grid_sync(int* bar, int target){
  __syncthreads();
  if (threadIdx.x == 0){
    __threadfence();   // release: drain + flush local caches (agent scope)
    __hip_atomic_fetch_add(bar, 1, __ATOMIC_RELAXED, __HIP_MEMORY_SCOPE_AGENT);
    while (__hip_atomic_fetch_add(bar, 0, __ATOMIC_RELAXED, __HIP_MEMORY_SCOPE_AGENT) < target)
      __builtin_amdgcn_s_sleep(4);
    __threadfence();   // acquire: invalidate local caches
  }
  __syncthreads();
}

__global__ __launch_bounds__(256, 1) void lstm_loop(
    const bf16_t* __restrict__ whh0,  // [4096][1024]
    const bf16_t* __restrict__ wih1,  // [4096][1024]
    const bf16_t* __restrict__ whh1,  // [4096][1024]
    const bf16_t* __restrict__ x0g,   // [64*128][4096]  (x@wih0^T + bias0)
    const float*  __restrict__ bias1, // [4096]
    const float*  __restrict__ c0in,  // [2][128][1024]
    bf16_t* __restrict__ h0rh, bf16_t* __restrict__ h0rl,  // ring [2][128][1024]
    bf16_t* __restrict__ h1h,  bf16_t* __restrict__ h1l,   // hist [65][128][1024]
    float* __restrict__ outH, float* __restrict__ outC,    // [2][128][1024]
    int* bar)
{
  __shared__ float sG[128*32];   // XOR-swizzled gate staging (16KB)
  const int tid = threadIdx.x, lane = tid & 63, w = tid >> 6;
  const int l15 = lane & 15, kg8 = (lane >> 4) << 3;
  const int hc0 = blockIdx.x * 8;

  // cell mapping: thread -> (crow, jjb..jjb+3)
  const int crow = tid >> 1, jjb = (tid & 1) * 4;

  // c-state registers
  float c0reg[4], c1reg[4];
  #pragma unroll
  for (int j=0;j<4;j++){
    c0reg[j] = c0in[(size_t)crow*1024 + hc0 + jjb + j];
    c1reg[j] = c0in[(size_t)131072 + (size_t)crow*1024 + hc0 + jjb + j];
  }

  // A-frag offsets (rows w*32 + m*16 + l15)
  const size_t aoff0 = (size_t)(w*32 + l15)*1024 + kg8;
  const size_t aoff1 = aoff0 + (size_t)16*1024;
  // B-frag offsets (same row structure for whh0/wih1/whh1)
  const int s0 = l15, s1 = 16 + l15;
  const size_t w0o = (size_t)(((s0>>3)<<10) + hc0 + (s0&7))*1024 + kg8;
  const size_t w1o = (size_t)(((s1>>3)<<10) + hc0 + (s1&7))*1024 + kg8;

  auto sg_addr = [&](int row, int col)->float*{
    return (float*)((char*)sG + row*128 + (((col<<2)) ^ ((row&7)<<4)));
  };

  for (int p = 0; p <= 64; ++p){
    const bool doA = (p < 64), doB = (p >= 1);
    const bf16_t* h0h_ = h0rh + (size_t)(p & 1)*131072;
    const bf16_t* h0l_ = h0rl + (size_t)(p & 1)*131072;
    const bf16_t* h1ph = h1h + (size_t)(doB ? p-1 : 0)*131072;
    const bf16_t* h1pl = h1l + (size_t)(doB ? p-1 : 0)*131072;

    f32x4 accA[2][2] = {};
    f32x4 accB[2][2] = {};

    // ---- section 0: K over h0[p-1]; feeds accA (whh0) and accB (wih1) ----
    #pragma unroll
    for (int ks = 0; ks < 32; ++ks){
      const int K0 = ks * 32;
      bf16x8 ah0 = *(const bf16x8*)(h0h_ + aoff0 + K0);
      bf16x8 ah1 = *(const bf16x8*)(h0h_ + aoff1 + K0);
      bf16x8 al0 = *(const bf16x8*)(h0l_ + aoff0 + K0);
      bf16x8 al1 = *(const bf16x8*)(h0l_ + aoff1 + K0);
      if (doA){
        bf16x8 b0 = *(const bf16x8*)(whh0 + w0o + K0);
        bf16x8 b1 = *(const bf16x8*)(whh0 + w1o + K0);
        MFMA16(accA[0][0], ah0, b0); MFMA16(accA[0][0], al0, b0);
        MFMA16(accA[1][0], ah1, b0); MFMA16(accA[1][0], al1, b0);
        MFMA16(accA[0][1], ah0, b1); MFMA16(accA[0][1], al0, b1);
        MFMA16(accA[1][1], ah1, b1); MFMA16(accA[1][1], al1, b1);
      }
      if (doB){
        bf16x8 d0 = *(const bf16x8*)(wih1 + w0o + K0);
        bf16x8 d1 = *(const bf16x8*)(wih1 + w1o + K0);
        MFMA16(accB[0][0], ah0, d0); MFMA16(accB[0][0], al0, d0);
        MFMA16(accB[1][0], ah1, d0); MFMA16(accB[1][0], al1, d0);
        MFMA16(accB[0][1], ah0, d1); MFMA16(accB[0][1], al0, d1);
        MFMA16(accB[1][1], ah1, d1); MFMA16(accB[1][1], al1, d1);
      }
    }
    // ---- section 1: K over h1[p-2] state; feeds accB (whh1) ----
    if (doB){
      #pragma unroll
      for (int ks = 0; ks < 32; ++ks){
        const int K0 = ks * 32;
        bf16x8 ah0 = *(const bf16x8*)(h1ph + aoff0 + K0);
        bf16x8 ah1 = *(const bf16x8*)(h1ph + aoff1 + K0);
        bf16x8 al0 = *(const bf16x8*)(h1pl + aoff0 + K0);
        bf16x8 al1 = *(const bf16x8*)(h1pl + aoff1 + K0);
        bf16x8 b0 = *(const bf16x8*)(whh1 + w0o + K0);
        bf16x8 b1 = *(const bf16x8*)(whh1 + w1o + K0);
        MFMA16(accB[0][0], ah0, b0); MFMA16(accB[0][0], al0, b0);
        MFMA16(accB[1][0], ah1, b0); MFMA16(accB[1][0], al1, b0);
        MFMA16(accB[0][1], ah0, b1); MFMA16(accB[0][1], al0, b1);
        MFMA16(accB[1][1], ah1, b1); MFMA16(accB[1][1], al1, b1);
      }
    }

    // ---- cell A (lstm0 step p) ----
    if (doA){
      #pragma unroll
      for (int m=0;m<2;m++)
        #pragma unroll
        for (int n=0;n<2;n++)
          #pragma unroll
          for (int r=0;r<4;r++){
            int row = w*32 + m*16 + ((lane>>4)<<2) + r;
            int col = n*16 + l15;
            *sg_addr(row, col) = accA[m][n][r];
          }
      __syncthreads();
      const bf16_t* xgp = x0g + ((size_t)p*128 + crow)*4096 + hc0 + jjb;
      bf16x4 xg0 = *(const bf16x4*)(xgp);
      bf16x4 xg1 = *(const bf16x4*)(xgp + 1024);
      bf16x4 xg2 = *(const bf16x4*)(xgp + 2048);
      bf16x4 xg3 = *(const bf16x4*)(xgp + 3072);
      bf16x4 hh, hl; float4 hf, cf;
      #pragma unroll
      for (int j=0;j<4;j++){
        int jj = jjb + j;
        float gi = *sg_addr(crow, jj)      + (float)xg0[j];
        float gf = *sg_addr(crow, 8+jj)    + (float)xg1[j];
        float gg = *sg_addr(crow, 16+jj)   + (float)xg2[j];
        float go = *sg_addr(crow, 24+jj)   + (float)xg3[j];
        float cv = sigm(gf)*c0reg[j] + sigm(gi)*tanhf(gg);
        float hv = sigm(go)*tanhf(cv);
        c0reg[j] = cv;
        hh[j] = (bf16_t)hv; hl[j] = (bf16_t)(hv - (float)hh[j]);
        (&hf.x)[j] = hv; (&cf.x)[j] = cv;
      }
      size_t ho = (size_t)crow*1024 + hc0 + jjb;
      bf16_t* h0nh = h0rh + (size_t)((p+1)&1)*131072;
      bf16_t* h0nl = h0rl + (size_t)((p+1)&1)*131072;
      *(bf16x4*)(h0nh + ho) = hh;
      *(bf16x4*)(h0nl + ho) = hl;
      if (p == 63){ *(float4*)(outH + ho) = hf; *(float4*)(outC + ho) = cf; }
      __syncthreads();
    }

    // ---- cell B (lstm1 step p-1) ----
    if (doB){
      #pragma unroll
      for (int m=0;m<2;m++)
        #pragma unroll
        for (int n=0;n<2;n++)
          #pragma unroll
          for (int r=0;r<4;r++){
            int row = w*32 + m*16 + ((lane>>4)<<2) + r;
            int col = n*16 + l15;
            *sg_addr(row, col) = accB[m][n][r];
          }
      __syncthreads();
      const float* bp = bias1 + hc0 + jjb;
      float4 b0v = *(const float4*)(bp);
      float4 b1v = *(const float4*)(bp + 1024);
      float4 b2v = *(const float4*)(bp + 2048);
      float4 b3v = *(const float4*)(bp + 3072);
      bf16x4 hh, hl; float4 hf, cf;
      #pragma unroll
      for (int j=0;j<4;j++){
        int jj = jjb + j;
        float gi = *sg_addr(crow, jj)      + (&b0v.x)[j];
        float gf = *sg_addr(crow, 8+jj)    + (&b1v.x)[j];
        float gg = *sg_addr(crow, 16+jj)   + (&b2v.x)[j];
        float go = *sg_addr(crow, 24+jj)   + (&b3v.x)[j];
        float cv = sigm(gf)*c1reg[j] + sigm(gi)*tanhf(gg);
        float hv = sigm(go)*tanhf(cv);
        c1reg[j] = cv;
        hh[j] = (bf16_t)hv; hl[j] = (bf16_t)(hv - (float)hh[j]);
        (&hf.x)[j] = hv; (&cf.x)[j] = cv;
      }
      size_t ho = (size_t)crow*1024 + hc0 + jjb;
      *(bf16x4*)(h1h + (size_t)p*131072 + ho) = hh;
      *(bf16x4*)(h1l + (size_t)p*131072 + ho) = hl;
      if (p == 64){
        *(float4*)(outH + 131072 + ho) = hf;
        *(float4*)(outC + 131072 + ho) = cf;
      }
      __syncthreads();
    }

    if (p < 64) grid_sync(bar, NBLK * (p + 1));
  }
}

// ---------------- scores + softmax (per batch row b), post-loop ----------------
__global__ __launch_bounds__(256) void attn_sm(
    const bf16_t* __restrict__ h1h, const bf16_t* __restrict__ h1l,
    const bf16_t* __restrict__ cwh, const bf16_t* __restrict__ cwl,
    float* __restrict__ a_all, float* __restrict__ outA)
{
  __shared__ bf16_t sAh[64*64], sAl[64*64];
  __shared__ bf16_t sBh[128*64], sBl[128*64];
  __shared__ float sS[64*128];
  int b = blockIdx.x;
  int tid = threadIdx.x, lane = tid&63, w = tid>>6;
  int wr = w>>1, wcc = w&1;
  f32x4 acc[2][4] = {};
  for (int kt=0; kt<1024; kt+=64){
    __syncthreads();
    #pragma unroll
    for (int i=0;i<2;i++){
      int c = i*256+tid; int r = c>>3, kk=(c&7)<<3;
      size_t src = (size_t)(r+1)*131072 + (size_t)b*1024 + kt+kk;
      gll16(h1h + src, sAh + (size_t)(i*256 + w*64)*8);
      gll16(h1l + src, sAl + (size_t)(i*256 + w*64)*8);
    }
    #pragma unroll
    for (int i=0;i<4;i++){
      int c = i*256+tid; int br=c>>3, kk=(c&7)<<3;
      size_t src = ((size_t)b*128 + br)*1024 + kt+kk;
      gll16(cwh + src, sBh + (size_t)(i*256+w*64)*8);
      gll16(cwl + src, sBl + (size_t)(i*256+w*64)*8);
    }
    __syncthreads();
    #pragma unroll
    for (int kk=0;kk<64;kk+=32){
      bf16x8 avh[2], avl[2], bvh[4], bvl[4];
      #pragma unroll
      for (int m=0;m<2;m++){
        int off = (wr*32 + m*16 + (lane&15))*64 + kk + ((lane>>4)<<3);
        avh[m] = *(const bf16x8*)(sAh + off);
        avl[m] = *(const bf16x8*)(sAl + off);
      }
      #pragma unroll
      for (int n=0;n<4;n++){
        int off = (wcc*64 + n*16 + (lane&15))*64 + kk + ((lane>>4)<<3);
        bvh[n] = *(const bf16x8*)(sBh + off);
        bvl[n] = *(const bf16x8*)(sBl + off);
      }
      #pragma unroll
      for (int m=0;m<2;m++)
        #pragma unroll
        for (int n=0;n<4;n++){
          acc[m][n] = __builtin_amdgcn_mfma_f32_16x16x32_bf16(avh[m], bvh[n], acc[m][n], 0,0,0);
          acc[m][n] = __builtin_amdgcn_mfma_f32_16x16x32_bf16(avl[m], bvh[n], acc[m][n], 0,0,0);
          acc[m][n] = __builtin_amdgcn_mfma_f32_16x16x32_bf16(avh[m], bvl[n], acc[m][n], 0,0,0);
        }
    }
  }
  #pragma unroll
  for (int m=0;m<2;m++)
    #pragma unroll
    for (int n=0;n<4;n++)
      #pragma unroll
      for (int r=0;r<4;r++){
        int trow = wr*32 + m*16 + ((lane>>4)<<2) + r;
        int tc   = wcc*64 + n*16 + (lane&15);
        sS[trow*128+tc] = acc[m][n][r];
      }
  __syncthreads();
  for (int i=0;i<16;i++){
    int r = w*16 + i;
    float v0 = sS[r*128 + lane], v1 = sS[r*128 + 64 + lane];
    float mx = fmaxf(v0, v1);
    #pragma unroll
    for (int off=32; off; off>>=1) mx = fmaxf(mx, __shfl_xor(mx, off));
    float e0 = expf(v0-mx), e1 = expf(v1-mx);
    float sm = e0+e1;
    #pragma unroll
    for (int off=32; off; off>>=1) sm += __shfl_xor(sm, off);
    float inv = 1.f/sm;
    size_t base = ((size_t)r*128 + b)*128;
    a_all[base + lane]      = e0*inv;
    a_all[base + 64 + lane] = e1*inv;
    if (r == 63){
      outA[(size_t)b*128 + lane]      = e0*inv;
      outA[(size_t)b*128 + 64 + lane] = e1*inv;
    }
  }
}

// ---------------- wc (fp32 VALU): wc[t,b,:] = sum_s a[t,b,s]*ctx[b,s,:] ----
__global__ __launch_bounds__(256) void wc_all(
    const float* __restrict__ a_all, const float* __restrict__ ctx,
    bf16_t* __restrict__ wch, bf16_t* __restrict__ wcl)
{
  int bid = blockIdx.x;
  int b = bid & 127, tg = bid >> 7;  // tg 0..3, 16 t each
  int tid = threadIdx.x;
  __shared__ float sa[16][128];
  int t0 = tg*16;
  #pragma unroll
  for (int i=0;i<8;i++){
    int q = i*256 + tid;
    int ti = q >> 7, s = q & 127;
    sa[ti][s] = a_all[((size_t)(t0+ti)*128 + b)*128 + s];
  }
  __syncthreads();
  f32x4 acc[16];
  #pragma unroll
  for (int i=0;i<16;i++) acc[i] = f32x4{0,0,0,0};
  const float* cb = ctx + (size_t)b*128*1024 + tid*4;
  for (int s=0;s<128;s++){
    f32x4 c = *(const f32x4*)(cb + (size_t)s*1024);
    #pragma unroll
    for (int ti=0;ti<16;ti++){
      float av = sa[ti][s];
      acc[ti] += av * c;
    }
  }
  #pragma unroll
  for (int ti=0;ti<16;ti++){
    size_t m = (size_t)(t0+ti)*128 + b;
    bf16x4 h, l;
    #pragma unroll
    for (int j=0;j<4;j++){
      float v = acc[ti][j];
      h[j] = (bf16_t)v; l[j] = (bf16_t)(v - (float)h[j]);
    }
    *(bf16x4*)(wch + m*1024 + tid*4) = h;
    *(bf16x4*)(wcl + m*1024 + tid*4) = l;
  }
}

// ---------------- host ----------------
extern "C" void kernel_launch(void* const* d_in, const int* in_sizes, int n_in,
                              void* d_out, int out_size, void* d_ws, size_t ws_size,
                              hipStream_t stream)
{
  (void)in_sizes; (void)n_in; (void)out_size; (void)ws_size;
  const int TT=64, BB=128, H=1024, G=4096, BH=128*1024;

  const int*   tok  = (const int*)d_in[0];
  const float* h0   = (const float*)d_in[1];
  const float* c0   = (const float*)d_in[2];
  const float* ctx  = (const float*)d_in[3];
  const float* embW = (const float*)d_in[5];
  const float* wih  = (const float*)d_in[6];
  const float* whh  = (const float*)d_in[7];
  const float* bih  = (const float*)d_in[8];
  const float* bhh  = (const float*)d_in[9];
  const float* Win  = (const float*)d_in[10];
  const float* Wout = (const float*)d_in[11];

  float* outY = (float*)d_out;                      // [T,B,H]
  float* outH = outY + (size_t)TT*BB*H;             // [2,B,H]
  float* outC = outH + (size_t)2*BH;                // [2,B,H]
  float* outA = outC + (size_t)2*BH;                // [B,S]

  char* ws = (char*)d_ws;
  size_t o = 0;
  auto carve = [&](size_t bytes)->char* {
    char* p = ws + o; o += (bytes + 255) & ~(size_t)255; return p;
  };
  bf16_t* wihB  = (bf16_t*)carve((size_t)2*G*H*2);       // 16MB
  bf16_t* whhB  = (bf16_t*)carve((size_t)2*G*H*2);       // 16MB
  bf16_t* woutH = (bf16_t*)carve((size_t)H*2*H*2);       // 4MB
  bf16_t* woutL = (bf16_t*)carve((size_t)H*2*H*2);       // 4MB
  bf16_t* winTh = (bf16_t*)carve((size_t)H*H*2);         // 2MB
  bf16_t* winTl = (bf16_t*)carve((size_t)H*H*2);         // 2MB
  bf16_t* ctxh  = (bf16_t*)carve((size_t)BB*128*H*2);    // 32MB (post-loop: wch)
  bf16_t* ctxl  = (bf16_t*)carve((size_t)BB*128*H*2);    // 32MB (post-loop: wcl)
  bf16_t* cwh   = (bf16_t*)carve((size_t)BB*128*H*2);    // 32MB (pre: xemb overlays)
  bf16_t* cwl   = (bf16_t*)carve((size_t)BB*128*H*2);    // 32MB
  bf16_t* x0g   = (bf16_t*)carve((size_t)TT*BB*G*2);     // 64MB
  bf16_t* h0rh  = (bf16_t*)carve((size_t)2*BH*2);        // ring, 2 slots
  bf16_t* h0rl  = (bf16_t*)carve((size_t)2*BH*2);
  bf16_t* h1h   = (bf16_t*)carve((size_t)(TT+1)*BH*2);   // 17MB history
  bf16_t* h1l   = (bf16_t*)carve((size_t)(TT+1)*BH*2);   // 17MB
  float*  a_all = (float*)carve((size_t)TT*BB*128*4);    // 4MB
  float*  biasF = (float*)carve((size_t)2*G*4);
  int*    bar   = (int*)carve(256);

  bf16_t* xemb = cwh;            // overlays ctxW-hi (dead until ctxW GEMM)
  bf16_t* wch  = ctxh;           // overlays ctx pair (dead post-loop)
  bf16_t* wcl  = ctxl;

  // ---- prep ----
  hipMemsetAsync(bar, 0, 256, stream);
  f2b<<<(2*G*H)/1024, 256, 0, stream>>>(wih, wihB, 2*G*H);
  f2b<<<(2*G*H)/1024, 256, 0, stream>>>(whh, whhB, 2*G*H);
  f2b_pair<<<(H*2*H)/1024, 256, 0, stream>>>(Wout, woutH, woutL, H*2*H);
  f2b_pair<<<(BB*128*H)/1024, 256, 0, stream>>>(ctx, ctxh, ctxl, BB*128*H);
  f2b_pair<<<BH/1024, 256, 0, stream>>>(h0, h0rh, h0rl, BH);
  f2b_pair<<<BH/1024, 256, 0, stream>>>(h0 + BH, h1h, h1l, BH);
  transWin<<<1024, 256, 0, stream>>>(Win, winTh, winTl);
  bias_combine<<<(2*G)/256, 256, 0, stream>>>(bih, bhh, biasF, 2*G);
  embed_gather<<<TT*BB, 256, 0, stream>>>(tok, embW, xemb);

  // ---- one-time GEMMs ----
  gemm_bt<<<(TT*BB/128)*(G/128), 256, 0, stream>>>(xemb, wihB, biasF, x0g, TT*BB, G, H, G/128);
  gemm_split<0,1><<<(BB*128/128)*(H/128), 256, 0, stream>>>(
      ctxh, ctxl, ctxh, ctxl, H, winTh, winTl,
      nullptr, cwh, cwl, BB*128, H, H, H/128);

  // ---- persistent recurrence ----
  lstm_loop<<<NBLK, 256, 0, stream>>>(
      whhB, wihB + (size_t)G*H, whhB + (size_t)G*H, x0g, biasF + G, c0,
      h0rh, h0rl, h1h, h1l, outH, outC, bar);

  // ---- post-loop attention ----
  attn_sm<<<BB, 256, 0, stream>>>(h1h, h1l, cwh, cwl, a_all, outA);
  wc_all<<<BB*4, 256, 0, stream>>>(a_all, ctx, wch, wcl);

  gemm_split<1,0><<<(TT*BB/128)*(H/128), 256, 0, stream>>>(
      wch, wcl, h1h + BH, h1l + BH, H, woutH, woutL,
      outY, nullptr, nullptr, TT*BB, H, 2*H, H/128);
}

// Round 4
// 4053.328 us; speedup vs baseline: 1.1815x; 1.1815x over previous
//
#include <hip/hip_runtime.h>
#include <hip/hip_bf16.h>
#include <stdint.h>

// Decoder: 2-layer LSTM + Luong attention. input_feed=0 => attention deferred
// post-loop. R4: persistent recurrence kernel, 256 blocks x 512 thr, ALL
// weights resident in LDS (99KB, loaded once, immune to per-phase L2
// invalidation), 2 waves/SIMD on all 256 CUs, h hi/lo split, c in registers.

typedef __bf16 bf16_t;
typedef __bf16 bf16x8 __attribute__((ext_vector_type(8)));
typedef __bf16 bf16x4 __attribute__((ext_vector_type(4)));
typedef float f32x4 __attribute__((ext_vector_type(4)));

#define AS1 __attribute__((address_space(1)))
#define AS3 __attribute__((address_space(3)))

__device__ __forceinline__ void gll16(const bf16_t* g, bf16_t* l) {
  __builtin_amdgcn_global_load_lds((const AS1 void*)g, (AS3 void*)l, 16, 0, 0);
}

__device__ __forceinline__ float sigm(float x){ return 1.f/(1.f+expf(-x)); }

#define MFMA16(acc, a, b) acc = __builtin_amdgcn_mfma_f32_16x16x32_bf16(a, b, acc, 0,0,0)

template<bool V> struct BC { static constexpr bool v = V; };

// ---------------- prep kernels ----------------
__global__ void f2b(const float* __restrict__ in, bf16_t* __restrict__ outp, int n){
  int i = (blockIdx.x*256 + threadIdx.x)*4;
  if (i >= n) return;
  float4 v = *(const float4*)(in + i);
  bf16x4 o; o[0]=(bf16_t)v.x; o[1]=(bf16_t)v.y; o[2]=(bf16_t)v.z; o[3]=(bf16_t)v.w;
  *(bf16x4*)(outp + i) = o;
}

__global__ void f2b_pair(const float* __restrict__ in, bf16_t* __restrict__ oh,
                         bf16_t* __restrict__ ol, int n){
  int i = (blockIdx.x*256 + threadIdx.x)*4;
  if (i >= n) return;
  float4 v = *(const float4*)(in + i);
  float vv[4] = {v.x, v.y, v.z, v.w};
  bf16x4 h, l;
  #pragma unroll
  for (int j=0;j<4;j++){ h[j]=(bf16_t)vv[j]; l[j]=(bf16_t)(vv[j]-(float)h[j]); }
  *(bf16x4*)(oh + i) = h;
  *(bf16x4*)(ol + i) = l;
}

__global__ void bias_combine(const float* __restrict__ a, const float* __restrict__ b,
                             float* __restrict__ o, int n){
  int i = blockIdx.x*256 + threadIdx.x;
  if (i < n) o[i] = a[i] + b[i];
}

__global__ void embed_gather(const int* __restrict__ tokp, const float* __restrict__ embW,
                             bf16_t* __restrict__ xe){
  int m = blockIdx.x;
  int tokv = tokp[m];
  const float* src = embW + (size_t)tokv*1024 + threadIdx.x*4;
  float4 v = *(const float4*)src;
  bf16x4 o; o[0]=(bf16_t)v.x; o[1]=(bf16_t)v.y; o[2]=(bf16_t)v.z; o[3]=(bf16_t)v.w;
  *(bf16x4*)(xe + (size_t)m*1024 + threadIdx.x*4) = o;
}

// winT[e,d] = split(Win[d,e])
__global__ void transWin(const float* __restrict__ in, bf16_t* __restrict__ oh,
                         bf16_t* __restrict__ ol){
  __shared__ float t[32][33];
  int bi = blockIdx.x & 31, bj = blockIdx.x >> 5;
  int tx = threadIdx.x & 31, ty = threadIdx.x >> 5;  // 32 x 8
  #pragma unroll
  for (int i=0;i<4;i++){
    int d = bi*32 + ty + i*8, e = bj*32 + tx;
    t[ty+i*8][tx] = in[(size_t)d*1024 + e];
  }
  __syncthreads();
  #pragma unroll
  for (int i=0;i<4;i++){
    int e = bj*32 + ty + i*8, d = bi*32 + tx;
    float v = t[tx][ty+i*8];
    bf16_t h = (bf16_t)v;
    oh[(size_t)e*1024 + d] = h;
    ol[(size_t)e*1024 + d] = (bf16_t)(v - (float)h);
  }
}

// ---------------- plain bf16 GEMM (x0g): C = A@B^T + bias, out bf16 ----------------
__global__ __launch_bounds__(256) void gemm_bt(
    const bf16_t* __restrict__ A, const bf16_t* __restrict__ Bm,
    const float* __restrict__ bias, bf16_t* __restrict__ Cout,
    int M, int N, int K, int nTN)
{
  __shared__ bf16_t sA[128*64];
  __shared__ bf16_t sB[128*64];
  int tid = threadIdx.x, lane = tid & 63, w = tid >> 6;
  int tm = blockIdx.x / nTN, tn = blockIdx.x % nTN;
  int row0 = tm*128, col0 = tn*128;
  int wr = w >> 1, wcc = w & 1;
  f32x4 acc[4][4] = {};
  for (int kt = 0; kt < K; kt += 64) {
    __syncthreads();
    #pragma unroll
    for (int i=0;i<4;i++){
      int c = i*256 + tid;
      int r = c >> 3, kk = (c & 7) << 3;
      gll16(A  + (size_t)(row0+r)*K + kt + kk, sA + (size_t)(i*256 + w*64)*8);
      gll16(Bm + (size_t)(col0+r)*K + kt + kk, sB + (size_t)(i*256 + w*64)*8);
    }
    __syncthreads();
    #pragma unroll
    for (int kk=0;kk<64;kk+=32){
      bf16x8 av[4], bv[4];
      #pragma unroll
      for (int m=0;m<4;m++) av[m] = *(const bf16x8*)(sA + (wr*64 + m*16 + (lane&15))*64 + kk + ((lane>>4)<<3));
      #pragma unroll
      for (int n=0;n<4;n++) bv[n] = *(const bf16x8*)(sB + (wcc*64 + n*16 + (lane&15))*64 + kk + ((lane>>4)<<3));
      #pragma unroll
      for (int m=0;m<4;m++)
        #pragma unroll
        for (int n=0;n<4;n++)
          acc[m][n] = __builtin_amdgcn_mfma_f32_16x16x32_bf16(av[m], bv[n], acc[m][n], 0,0,0);
    }
  }
  #pragma unroll
  for (int n=0;n<4;n++){
    int cn = col0 + wcc*64 + n*16 + (lane & 15);
    float bvv = bias[cn];
    #pragma unroll
    for (int m=0;m<4;m++){
      int rm = row0 + wr*64 + m*16 + ((lane>>4)<<2);
      #pragma unroll
      for (int r=0;r<4;r++)
        Cout[(size_t)(rm+r)*N + cn] = (bf16_t)(acc[m][n][r] + bvv);
    }
  }
}

// ---------------- split GEMM: hi/lo A (two K-parts) x hi/lo B, 3 combos ----------------
template<int ACT_TANH, int OUT_PAIR>
__global__ __launch_bounds__(256) void gemm_split(
    const bf16_t* __restrict__ Ah1, const bf16_t* __restrict__ Al1,
    const bf16_t* __restrict__ Ah2, const bf16_t* __restrict__ Al2, int K1,
    const bf16_t* __restrict__ Bh, const bf16_t* __restrict__ Bl,
    float* __restrict__ Cf, bf16_t* __restrict__ Ch, bf16_t* __restrict__ Cl,
    int M, int N, int K, int nTN)
{
  __shared__ bf16_t sAh[128*64], sAl[128*64], sBh[128*64], sBl[128*64];
  int tid = threadIdx.x, lane = tid & 63, w = tid >> 6;
  int tm = blockIdx.x / nTN, tn = blockIdx.x % nTN;
  int row0 = tm*128, col0 = tn*128;
  int wr = w >> 1, wcc = w & 1;
  f32x4 acc[4][4] = {};
  for (int kt = 0; kt < K; kt += 64) {
    const bf16_t *Ah, *Al; int kl;
    if (kt < K1){ Ah=Ah1; Al=Al1; kl=kt; } else { Ah=Ah2; Al=Al2; kl=kt-K1; }
    __syncthreads();
    #pragma unroll
    for (int i=0;i<4;i++){
      int c = i*256 + tid;
      int r = c >> 3, kk = (c & 7) << 3;
      gll16(Ah + (size_t)(row0+r)*K1 + kl + kk, sAh + (size_t)(i*256 + w*64)*8);
      gll16(Al + (size_t)(row0+r)*K1 + kl + kk, sAl + (size_t)(i*256 + w*64)*8);
      gll16(Bh + (size_t)(col0+r)*K + kt + kk, sBh + (size_t)(i*256 + w*64)*8);
      gll16(Bl + (size_t)(col0+r)*K + kt + kk, sBl + (size_t)(i*256 + w*64)*8);
    }
    __syncthreads();
    #pragma unroll
    for (int kk=0;kk<64;kk+=32){
      bf16x8 avh[4], avl[4], bvh[4], bvl[4];
      #pragma unroll
      for (int m=0;m<4;m++){
        int off = (wr*64 + m*16 + (lane&15))*64 + kk + ((lane>>4)<<3);
        avh[m] = *(const bf16x8*)(sAh + off);
        avl[m] = *(const bf16x8*)(sAl + off);
      }
      #pragma unroll
      for (int n=0;n<4;n++){
        int off = (wcc*64 + n*16 + (lane&15))*64 + kk + ((lane>>4)<<3);
        bvh[n] = *(const bf16x8*)(sBh + off);
        bvl[n] = *(const bf16x8*)(sBl + off);
      }
      #pragma unroll
      for (int m=0;m<4;m++)
        #pragma unroll
        for (int n=0;n<4;n++){
          acc[m][n] = __builtin_amdgcn_mfma_f32_16x16x32_bf16(avh[m], bvh[n], acc[m][n], 0,0,0);
          acc[m][n] = __builtin_amdgcn_mfma_f32_16x16x32_bf16(avl[m], bvh[n], acc[m][n], 0,0,0);
          acc[m][n] = __builtin_amdgcn_mfma_f32_16x16x32_bf16(avh[m], bvl[n], acc[m][n], 0,0,0);
        }
    }
  }
  #pragma unroll
  for (int n=0;n<4;n++){
    int cn = col0 + wcc*64 + n*16 + (lane & 15);
    #pragma unroll
    for (int m=0;m<4;m++){
      int rm = row0 + wr*64 + m*16 + ((lane>>4)<<2);
      #pragma unroll
      for (int r=0;r<4;r++){
        float v = acc[m][n][r];
        if (ACT_TANH) v = tanhf(v);
        if (OUT_PAIR){
          bf16_t h = (bf16_t)v;
          Ch[(size_t)(rm+r)*N + cn] = h;
          Cl[(size_t)(rm+r)*N + cn] = (bf16_t)(v - (float)h);
        } else {
          Cf[(size_t)(rm+r)*N + cn] = v;
        }
      }
    }
  }
}

// ---------------- persistent LSTM loop kernel ----------------
// 256 blocks x 512 thr (8 waves). Block owns 4 hidden cols (16 gate rows per
// matrix, both layers). Weights in LDS (loaded once). Wave w: batch rows
// [w*16,w*16+16), all 16 gate cols. Phase p: layer0 step p + layer1 step p-1
// sharing h0[p-1] A-frag loads. c-state: 1 cell per thread, in registers.
#define NBLK 256

__device__ __forceinline__ void grid_sync(int* bar, int target){
  __syncthreads();
  if (threadIdx.x == 0){
    __threadfence();   // release (flush L1/L2 to coherence point)
    __hip_atomic_fetch_add(bar, 1, __ATOMIC_RELAXED, __HIP_MEMORY_SCOPE_AGENT);
    while (__hip_atomic_load(bar, __ATOMIC_RELAXED, __HIP_MEMORY_SCOPE_AGENT) < target)
      __builtin_amdgcn_s_sleep(1);
    __threadfence();   // acquire (invalidate local caches)
  }
  __syncthreads();
}

// LDS: weights [48 rows][1032 bf16]  (stride 2064B, mod128=16 -> uniform banks)
//      rows: m*16+n, m in {0:whh0,1:wih1,2:whh1}, n = g*4+q (gate g, col q)
//      sG:   [128][17] f32 gate staging
#define WSTRIDE 1032
#define SG_OFF  99072
#define LDS_BYTES 107776

__global__ __launch_bounds__(512, 2) void lstm_loop(
    const bf16_t* __restrict__ whh0,  // [4096][1024]
    const bf16_t* __restrict__ wih1,  // [4096][1024]
    const bf16_t* __restrict__ whh1,  // [4096][1024]
    const bf16_t* __restrict__ x0g,   // [64*128][4096]
    const float*  __restrict__ bias1, // [4096]
    const float*  __restrict__ c0in,  // [2][128][1024]
    bf16_t* __restrict__ h0rh, bf16_t* __restrict__ h0rl,  // ring [2][128][1024]
    bf16_t* __restrict__ h1h,  bf16_t* __restrict__ h1l,   // hist [65][128][1024]
    float* __restrict__ outH, float* __restrict__ outC,    // [2][128][1024]
    int* bar)
{
  extern __shared__ char smem[];
  bf16_t* wlds = (bf16_t*)smem;
  float*  sG   = (float*)(smem + SG_OFF);

  const int tid = threadIdx.x, lane = tid & 63, wv = tid >> 6;
  const int l15 = lane & 15, hi4 = lane >> 4, kg8 = hi4 << 3;
  const int hc0 = blockIdx.x * 4;

  // ---- stage weights into LDS once ----
  for (int e = tid; e < 6144; e += 512){
    int m = e >> 11, r = e & 2047, n = r >> 7, kc = r & 127;
    const bf16_t* Wm = (m == 0) ? whh0 : ((m == 1) ? wih1 : whh1);
    int row = ((n >> 2) << 10) + hc0 + (n & 3);
    bf16x8 v = *(const bf16x8*)(Wm + (size_t)row*1024 + kc*8);
    *(bf16x8*)(wlds + (m*16 + n)*WSTRIDE + kc*8) = v;
  }
  __syncthreads();

  // cell mapping: 1 cell per thread
  const int crow = tid >> 2, q = tid & 3;
  const size_t cellix = (size_t)crow*1024 + hc0 + q;

  float c0reg = c0in[cellix];
  float c1reg = c0in[131072 + cellix];
  float bs0 = bias1[hc0 + q],        bs1 = bias1[1024 + hc0 + q];
  float bs2 = bias1[2048 + hc0 + q], bs3 = bias1[3072 + hc0 + q];

  const size_t aoff = (size_t)(wv*16 + l15)*1024 + kg8;
  const int dsA = (0*16 + l15)*WSTRIDE + kg8;
  const int dsB = (1*16 + l15)*WSTRIDE + kg8;
  const int dsC = (2*16 + l15)*WSTRIDE + kg8;

  for (int p = 0; p <= 64; ++p){
    const bf16_t* h0h_ = h0rh + (size_t)(p & 1)*131072;
    const bf16_t* h0l_ = h0rl + (size_t)(p & 1)*131072;
    const bf16_t* h1ph = h1h + (size_t)(p >= 1 ? p-1 : 0)*131072;
    const bf16_t* h1pl = h1l + (size_t)(p >= 1 ? p-1 : 0)*131072;

    auto phase = [&](auto doa, auto dob){
      constexpr bool DOA = decltype(doa)::v;
      constexpr bool DOB = decltype(dob)::v;

      // hoist x0g loads (constant data, L3-latency hidden under GEMM)
      float xg0=0, xg1=0, xg2=0, xg3=0;
      if (DOA){
        const bf16_t* xp = x0g + ((size_t)p*128 + crow)*4096 + hc0 + q;
        xg0 = (float)xp[0];    xg1 = (float)xp[1024];
        xg2 = (float)xp[2048]; xg3 = (float)xp[3072];
      }

      f32x4 accA = {}, accB = {};

      // section 0: K over h0[p-1]; feeds accA (whh0) and accB (wih1)
      #pragma unroll
      for (int ks = 0; ks < 32; ++ks){
        const int K0 = ks * 32;
        bf16x8 ah = *(const bf16x8*)(h0h_ + aoff + K0);
        bf16x8 al = *(const bf16x8*)(h0l_ + aoff + K0);
        if (DOA){
          bf16x8 b = *(const bf16x8*)(wlds + dsA + K0);
          MFMA16(accA, ah, b); MFMA16(accA, al, b);
        }
        if (DOB){
          bf16x8 b = *(const bf16x8*)(wlds + dsB + K0);
          MFMA16(accB, ah, b); MFMA16(accB, al, b);
        }
      }
      // section 1: K over h1[p-2]; feeds accB (whh1)
      if (DOB){
        #pragma unroll
        for (int ks = 0; ks < 32; ++ks){
          const int K0 = ks * 32;
          bf16x8 ah = *(const bf16x8*)(h1ph + aoff + K0);
          bf16x8 al = *(const bf16x8*)(h1pl + aoff + K0);
          bf16x8 b = *(const bf16x8*)(wlds + dsC + K0);
          MFMA16(accB, ah, b); MFMA16(accB, al, b);
        }
      }

      // ---- cell A (lstm0 step p) ----
      if (DOA){
        #pragma unroll
        for (int r=0;r<4;r++) sG[(wv*16 + hi4*4 + r)*17 + l15] = accA[r];
        __syncthreads();
        float gi = sG[crow*17 + q]      + xg0;
        float gf = sG[crow*17 + 4 + q]  + xg1;
        float gg = sG[crow*17 + 8 + q]  + xg2;
        float go = sG[crow*17 + 12 + q] + xg3;
        float cv = sigm(gf)*c0reg + sigm(gi)*tanhf(gg);
        float hv = sigm(go)*tanhf(cv);
        c0reg = cv;
        bf16_t hh = (bf16_t)hv;
        bf16_t* h0nh = h0rh + (size_t)((p+1)&1)*131072;
        bf16_t* h0nl = h0rl + (size_t)((p+1)&1)*131072;
        h0nh[cellix] = hh;
        h0nl[cellix] = (bf16_t)(hv - (float)hh);
        if (p == 63){ outH[cellix] = hv; outC[cellix] = cv; }
        __syncthreads();
      }

      // ---- cell B (lstm1 step p-1) ----
      if (DOB){
        #pragma unroll
        for (int r=0;r<4;r++) sG[(wv*16 + hi4*4 + r)*17 + l15] = accB[r];
        __syncthreads();
        float gi = sG[crow*17 + q]      + bs0;
        float gf = sG[crow*17 + 4 + q]  + bs1;
        float gg = sG[crow*17 + 8 + q]  + bs2;
        float go = sG[crow*17 + 12 + q] + bs3;
        float cv = sigm(gf)*c1reg + sigm(gi)*tanhf(gg);
        float hv = sigm(go)*tanhf(cv);
        c1reg = cv;
        bf16_t hh = (bf16_t)hv;
        h1h[(size_t)p*131072 + cellix] = hh;
        h1l[(size_t)p*131072 + cellix] = (bf16_t)(hv - (float)hh);
        if (p == 64){ outH[131072 + cellix] = hv; outC[131072 + cellix] = cv; }
        __syncthreads();
      }
    };

    if (p == 0)       phase(BC<true>{},  BC<false>{});
    else if (p < 64)  phase(BC<true>{},  BC<true>{});
    else              phase(BC<false>{}, BC<true>{});

    if (p < 64) grid_sync(bar, NBLK * (p + 1));
  }
}

// ---------------- scores + softmax (per batch row b), post-loop ----------------
__global__ __launch_bounds__(256) void attn_sm(
    const bf16_t* __restrict__ h1h, const bf16_t* __restrict__ h1l,
    const bf16_t* __restrict__ cwh, const bf16_t* __restrict__ cwl,
    float* __restrict__ a_all, float* __restrict__ outA)
{
  __shared__ bf16_t sAh[64*64], sAl[64*64];
  __shared__ bf16_t sBh[128*64], sBl[128*64];
  __shared__ float sS[64*128];
  int b = blockIdx.x;
  int tid = threadIdx.x, lane = tid&63, w = tid>>6;
  int wr = w>>1, wcc = w&1;
  f32x4 acc[2][4] = {};
  for (int kt=0; kt<1024; kt+=64){
    __syncthreads();
    #pragma unroll
    for (int i=0;i<2;i++){
      int c = i*256+tid; int r = c>>3, kk=(c&7)<<3;
      size_t src = (size_t)(r+1)*131072 + (size_t)b*1024 + kt+kk;
      gll16(h1h + src, sAh + (size_t)(i*256 + w*64)*8);
      gll16(h1l + src, sAl + (size_t)(i*256 + w*64)*8);
    }
    #pragma unroll
    for (int i=0;i<4;i++){
      int c = i*256+tid; int br=c>>3, kk=(c&7)<<3;
      size_t src = ((size_t)b*128 + br)*1024 + kt+kk;
      gll16(cwh + src, sBh + (size_t)(i*256+w*64)*8);
      gll16(cwl + src, sBl + (size_t)(i*256+w*64)*8);
    }
    __syncthreads();
    #pragma unroll
    for (int kk=0;kk<64;kk+=32){
      bf16x8 avh[2], avl[2], bvh[4], bvl[4];
      #pragma unroll
      for (int m=0;m<2;m++){
        int off = (wr*32 + m*16 + (lane&15))*64 + kk + ((lane>>4)<<3);
        avh[m] = *(const bf16x8*)(sAh + off);
        avl[m] = *(const bf16x8*)(sAl + off);
      }
      #pragma unroll
      for (int n=0;n<4;n++){
        int off = (wcc*64 + n*16 + (lane&15))*64 + kk + ((lane>>4)<<3);
        bvh[n] = *(const bf16x8*)(sBh + off);
        bvl[n] = *(const bf16x8*)(sBl + off);
      }
      #pragma unroll
      for (int m=0;m<2;m++)
        #pragma unroll
        for (int n=0;n<4;n++){
          acc[m][n] = __builtin_amdgcn_mfma_f32_16x16x32_bf16(avh[m], bvh[n], acc[m][n], 0,0,0);
          acc[m][n] = __builtin_amdgcn_mfma_f32_16x16x32_bf16(avl[m], bvh[n], acc[m][n], 0,0,0);
          acc[m][n] = __builtin_amdgcn_mfma_f32_16x16x32_bf16(avh[m], bvl[n], acc[m][n], 0,0,0);
        }
    }
  }
  #pragma unroll
  for (int m=0;m<2;m++)
    #pragma unroll
    for (int n=0;n<4;n++)
      #pragma unroll
      for (int r=0;r<4;r++){
        int trow = wr*32 + m*16 + ((lane>>4)<<2) + r;
        int tc   = wcc*64 + n*16 + (lane&15);
        sS[trow*128+tc] = acc[m][n][r];
      }
  __syncthreads();
  for (int i=0;i<16;i++){
    int r = w*16 + i;
    float v0 = sS[r*128 + lane], v1 = sS[r*128 + 64 + lane];
    float mx = fmaxf(v0, v1);
    #pragma unroll
    for (int off=32; off; off>>=1) mx = fmaxf(mx, __shfl_xor(mx, off));
    float e0 = expf(v0-mx), e1 = expf(v1-mx);
    float sm = e0+e1;
    #pragma unroll
    for (int off=32; off; off>>=1) sm += __shfl_xor(sm, off);
    float inv = 1.f/sm;
    size_t base = ((size_t)r*128 + b)*128;
    a_all[base + lane]      = e0*inv;
    a_all[base + 64 + lane] = e1*inv;
    if (r == 63){
      outA[(size_t)b*128 + lane]      = e0*inv;
      outA[(size_t)b*128 + 64 + lane] = e1*inv;
    }
  }
}

// ---------------- wc (fp32 VALU): wc[t,b,:] = sum_s a[t,b,s]*ctx[b,s,:] ----
__global__ __launch_bounds__(256) void wc_all(
    const float* __restrict__ a_all, const float* __restrict__ ctx,
    bf16_t* __restrict__ wch, bf16_t* __restrict__ wcl)
{
  int bid = blockIdx.x;
  int b = bid & 127, tg = bid >> 7;  // tg 0..3, 16 t each
  int tid = threadIdx.x;
  __shared__ float sa[16][128];
  int t0 = tg*16;
  #pragma unroll
  for (int i=0;i<8;i++){
    int q = i*256 + tid;
    int ti = q >> 7, s = q & 127;
    sa[ti][s] = a_all[((size_t)(t0+ti)*128 + b)*128 + s];
  }
  __syncthreads();
  f32x4 acc[16];
  #pragma unroll
  for (int i=0;i<16;i++) acc[i] = f32x4{0,0,0,0};
  const float* cb = ctx + (size_t)b*128*1024 + tid*4;
  for (int s=0;s<128;s++){
    f32x4 c = *(const f32x4*)(cb + (size_t)s*1024);
    #pragma unroll
    for (int ti=0;ti<16;ti++){
      float av = sa[ti][s];
      acc[ti] += av * c;
    }
  }
  #pragma unroll
  for (int ti=0;ti<16;ti++){
    size_t m = (size_t)(t0+ti)*128 + b;
    bf16x4 h, l;
    #pragma unroll
    for (int j=0;j<4;j++){
      float v = acc[ti][j];
      h[j] = (bf16_t)v; l[j] = (bf16_t)(v - (float)h[j]);
    }
    *(bf16x4*)(wch + m*1024 + tid*4) = h;
    *(bf16x4*)(wcl + m*1024 + tid*4) = l;
  }
}

// ---------------- host ----------------
extern "C" void kernel_launch(void* const* d_in, const int* in_sizes, int n_in,
                              void* d_out, int out_size, void* d_ws, size_t ws_size,
                              hipStream_t stream)
{
  (void)in_sizes; (void)n_in; (void)out_size; (void)ws_size;
  const int TT=64, BB=128, H=1024, G=4096, BH=128*1024;

  const int*   tok  = (const int*)d_in[0];
  const float* h0   = (const float*)d_in[1];
  const float* c0   = (const float*)d_in[2];
  const float* ctx  = (const float*)d_in[3];
  const float* embW = (const float*)d_in[5];
  const float* wih  = (const float*)d_in[6];
  const float* whh  = (const float*)d_in[7];
  const float* bih  = (const float*)d_in[8];
  const float* bhh  = (const float*)d_in[9];
  const float* Win  = (const float*)d_in[10];
  const float* Wout = (const float*)d_in[11];

  float* outY = (float*)d_out;                      // [T,B,H]
  float* outH = outY + (size_t)TT*BB*H;             // [2,B,H]
  float* outC = outH + (size_t)2*BH;                // [2,B,H]
  float* outA = outC + (size_t)2*BH;                // [B,S]

  char* ws = (char*)d_ws;
  size_t o = 0;
  auto carve = [&](size_t bytes)->char* {
    char* p = ws + o; o += (bytes + 255) & ~(size_t)255; return p;
  };
  bf16_t* wihB  = (bf16_t*)carve((size_t)2*G*H*2);       // 16MB
  bf16_t* whhB  = (bf16_t*)carve((size_t)2*G*H*2);       // 16MB
  bf16_t* woutH = (bf16_t*)carve((size_t)H*2*H*2);       // 4MB
  bf16_t* woutL = (bf16_t*)carve((size_t)H*2*H*2);       // 4MB
  bf16_t* winTh = (bf16_t*)carve((size_t)H*H*2);         // 2MB
  bf16_t* winTl = (bf16_t*)carve((size_t)H*H*2);         // 2MB
  bf16_t* ctxh  = (bf16_t*)carve((size_t)BB*128*H*2);    // 32MB (post-loop: wch)
  bf16_t* ctxl  = (bf16_t*)carve((size_t)BB*128*H*2);    // 32MB (post-loop: wcl)
  bf16_t* cwh   = (bf16_t*)carve((size_t)BB*128*H*2);    // 32MB (pre: xemb overlays)
  bf16_t* cwl   = (bf16_t*)carve((size_t)BB*128*H*2);    // 32MB
  bf16_t* x0g   = (bf16_t*)carve((size_t)TT*BB*G*2);     // 64MB
  bf16_t* h0rh  = (bf16_t*)carve((size_t)2*BH*2);        // ring, 2 slots
  bf16_t* h0rl  = (bf16_t*)carve((size_t)2*BH*2);
  bf16_t* h1h   = (bf16_t*)carve((size_t)(TT+1)*BH*2);   // 17MB history
  bf16_t* h1l   = (bf16_t*)carve((size_t)(TT+1)*BH*2);   // 17MB
  float*  a_all = (float*)carve((size_t)TT*BB*128*4);    // 4MB
  float*  biasF = (float*)carve((size_t)2*G*4);
  int*    bar   = (int*)carve(256);

  bf16_t* xemb = cwh;            // overlays ctxW-hi (dead until ctxW GEMM)
  bf16_t* wch  = ctxh;           // overlays ctx pair (dead post-loop)
  bf16_t* wcl  = ctxl;

  // ---- prep ----
  hipMemsetAsync(bar, 0, 256, stream);
  f2b<<<(2*G*H)/1024, 256, 0, stream>>>(wih, wihB, 2*G*H);
  f2b<<<(2*G*H)/1024, 256, 0, stream>>>(whh, whhB, 2*G*H);
  f2b_pair<<<(H*2*H)/1024, 256, 0, stream>>>(Wout, woutH, woutL, H*2*H);
  f2b_pair<<<(BB*128*H)/1024, 256, 0, stream>>>(ctx, ctxh, ctxl, BB*128*H);
  f2b_pair<<<BH/1024, 256, 0, stream>>>(h0, h0rh, h0rl, BH);
  f2b_pair<<<BH/1024, 256, 0, stream>>>(h0 + BH, h1h, h1l, BH);
  transWin<<<1024, 256, 0, stream>>>(Win, winTh, winTl);
  bias_combine<<<(2*G)/256, 256, 0, stream>>>(bih, bhh, biasF, 2*G);
  embed_gather<<<TT*BB, 256, 0, stream>>>(tok, embW, xemb);

  // ---- one-time GEMMs ----
  gemm_bt<<<(TT*BB/128)*(G/128), 256, 0, stream>>>(xemb, wihB, biasF, x0g, TT*BB, G, H, G/128);
  gemm_split<0,1><<<(BB*128/128)*(H/128), 256, 0, stream>>>(
      ctxh, ctxl, ctxh, ctxl, H, winTh, winTl,
      nullptr, cwh, cwl, BB*128, H, H, H/128);

  // ---- persistent recurrence (dynamic LDS 107776B: weights 99KB + sG) ----
  hipFuncSetAttribute((const void*)lstm_loop,
                      hipFuncAttributeMaxDynamicSharedMemorySize, LDS_BYTES);
  lstm_loop<<<NBLK, 512, LDS_BYTES, stream>>>(
      whhB, wihB + (size_t)G*H, whhB + (size_t)G*H, x0g, biasF + G, c0,
      h0rh, h0rl, h1h, h1l, outH, outC, bar);

  // ---- post-loop attention ----
  attn_sm<<<BB, 256, 0, stream>>>(h1h, h1l, cwh, cwl, a_all, outA);
  wc_all<<<BB*4, 256, 0, stream>>>(a_all, ctx, wch, wcl);

  gemm_split<1,0><<<(TT*BB/128)*(H/128), 256, 0, stream>>>(
      wch, wcl, h1h + BH, h1l + BH, H, woutH, woutL,
      outY, nullptr, nullptr, TT*BB, H, 2*H, H/128);
}

// Round 5
// 2353.210 us; speedup vs baseline: 2.0351x; 1.7225x over previous
//
#include <hip/hip_runtime.h>
#include <hip/hip_bf16.h>
#include <stdint.h>

// Decoder: 2-layer LSTM + Luong attention. input_feed=0 => attention deferred
// post-loop. R5: persistent recurrence, batch-partitioned (8 bg x 32 cg = 256
// blocks, 1/CU). h-state communicated via sc0sc1 write-through stores +
// L2-bypass staged loads => NO threadfences, L2 stays warm for weights.
// x0g transposed for dense per-phase reads. c-state 1 cell/thread in regs.

typedef __bf16 bf16_t;
typedef __bf16 bf16x8 __attribute__((ext_vector_type(8)));
typedef __bf16 bf16x4 __attribute__((ext_vector_type(4)));
typedef float f32x4 __attribute__((ext_vector_type(4)));

#define AS1 __attribute__((address_space(1)))
#define AS3 __attribute__((address_space(3)))

__device__ __forceinline__ void gll16(const bf16_t* g, bf16_t* l) {
  __builtin_amdgcn_global_load_lds((const AS1 void*)g, (AS3 void*)l, 16, 0, 0);
}

__device__ __forceinline__ float sigm(float x){ return 1.f/(1.f+expf(-x)); }

#define MFMA16(acc, a, b) acc = __builtin_amdgcn_mfma_f32_16x16x32_bf16(a, b, acc, 0,0,0)

// ---- coherent (L2-bypass / write-through) access helpers ----
__device__ __forceinline__ bf16x8 ldg_sc(const bf16_t* p){
  f32x4 r;
  asm volatile("global_load_dwordx4 %0, %1, off sc0 sc1" : "=v"(r) : "v"(p));
  return __builtin_bit_cast(bf16x8, r);
}
__device__ __forceinline__ void stg_sc(bf16_t* p, bf16_t v){
  uint32_t w = (uint32_t)__builtin_bit_cast(uint16_t, v);
  asm volatile("global_store_short %0, %1, off sc0 sc1" :: "v"(p), "v"(w) : "memory");
}

// ---------------- prep kernels ----------------
__global__ void f2b(const float* __restrict__ in, bf16_t* __restrict__ outp, int n){
  int i = (blockIdx.x*256 + threadIdx.x)*4;
  if (i >= n) return;
  float4 v = *(const float4*)(in + i);
  bf16x4 o; o[0]=(bf16_t)v.x; o[1]=(bf16_t)v.y; o[2]=(bf16_t)v.z; o[3]=(bf16_t)v.w;
  *(bf16x4*)(outp + i) = o;
}

__global__ void f2b_pair(const float* __restrict__ in, bf16_t* __restrict__ oh,
                         bf16_t* __restrict__ ol, int n){
  int i = (blockIdx.x*256 + threadIdx.x)*4;
  if (i >= n) return;
  float4 v = *(const float4*)(in + i);
  float vv[4] = {v.x, v.y, v.z, v.w};
  bf16x4 h, l;
  #pragma unroll
  for (int j=0;j<4;j++){ h[j]=(bf16_t)vv[j]; l[j]=(bf16_t)(vv[j]-(float)h[j]); }
  *(bf16x4*)(oh + i) = h;
  *(bf16x4*)(ol + i) = l;
}

__global__ void bias_combine(const float* __restrict__ a, const float* __restrict__ b,
                             float* __restrict__ o, int n){
  int i = blockIdx.x*256 + threadIdx.x;
  if (i < n) o[i] = a[i] + b[i];
}

__global__ void embed_gather(const int* __restrict__ tokp, const float* __restrict__ embW,
                             bf16_t* __restrict__ xe){
  int m = blockIdx.x;
  int tokv = tokp[m];
  const float* src = embW + (size_t)tokv*1024 + threadIdx.x*4;
  float4 v = *(const float4*)src;
  bf16x4 o; o[0]=(bf16_t)v.x; o[1]=(bf16_t)v.y; o[2]=(bf16_t)v.z; o[3]=(bf16_t)v.w;
  *(bf16x4*)(xe + (size_t)m*1024 + threadIdx.x*4) = o;
}

// winT[e,d] = split(Win[d,e])
__global__ void transWin(const float* __restrict__ in, bf16_t* __restrict__ oh,
                         bf16_t* __restrict__ ol){
  __shared__ float t[32][33];
  int bi = blockIdx.x & 31, bj = blockIdx.x >> 5;
  int tx = threadIdx.x & 31, ty = threadIdx.x >> 5;  // 32 x 8
  #pragma unroll
  for (int i=0;i<4;i++){
    int d = bi*32 + ty + i*8, e = bj*32 + tx;
    t[ty+i*8][tx] = in[(size_t)d*1024 + e];
  }
  __syncthreads();
  #pragma unroll
  for (int i=0;i<4;i++){
    int e = bj*32 + ty + i*8, d = bi*32 + tx;
    float v = t[tx][ty+i*8];
    bf16_t h = (bf16_t)v;
    oh[(size_t)e*1024 + d] = h;
    ol[(size_t)e*1024 + d] = (bf16_t)(v - (float)h);
  }
}

// -------- x0g GEMM: x0gT[t][bg][g][col][16 rows] = xemb@wih0^T + bias0 --------
__global__ __launch_bounds__(256) void gemm_bt(
    const bf16_t* __restrict__ A, const bf16_t* __restrict__ Bm,
    const float* __restrict__ bias, bf16_t* __restrict__ Cout,
    int M, int N, int K, int nTN)
{
  __shared__ bf16_t sA[128*64];
  __shared__ bf16_t sB[128*64];
  int tid = threadIdx.x, lane = tid & 63, w = tid >> 6;
  int tm = blockIdx.x / nTN, tn = blockIdx.x % nTN;
  int row0 = tm*128, col0 = tn*128;
  int wr = w >> 1, wcc = w & 1;
  f32x4 acc[4][4] = {};
  for (int kt = 0; kt < K; kt += 64) {
    __syncthreads();
    #pragma unroll
    for (int i=0;i<4;i++){
      int c = i*256 + tid;
      int r = c >> 3, kk = (c & 7) << 3;
      gll16(A  + (size_t)(row0+r)*K + kt + kk, sA + (size_t)(i*256 + w*64)*8);
      gll16(Bm + (size_t)(col0+r)*K + kt + kk, sB + (size_t)(i*256 + w*64)*8);
    }
    __syncthreads();
    #pragma unroll
    for (int kk=0;kk<64;kk+=32){
      bf16x8 av[4], bv[4];
      #pragma unroll
      for (int m=0;m<4;m++) av[m] = *(const bf16x8*)(sA + (wr*64 + m*16 + (lane&15))*64 + kk + ((lane>>4)<<3));
      #pragma unroll
      for (int n=0;n<4;n++) bv[n] = *(const bf16x8*)(sB + (wcc*64 + n*16 + (lane&15))*64 + kk + ((lane>>4)<<3));
      #pragma unroll
      for (int m=0;m<4;m++)
        #pragma unroll
        for (int n=0;n<4;n++)
          acc[m][n] = __builtin_amdgcn_mfma_f32_16x16x32_bf16(av[m], bv[n], acc[m][n], 0,0,0);
    }
  }
  #pragma unroll
  for (int n=0;n<4;n++){
    int cn = col0 + wcc*64 + n*16 + (lane & 15);
    float bvv = bias[cn];
    int g = cn >> 10, col = cn & 1023;
    #pragma unroll
    for (int m=0;m<4;m++){
      int rm = row0 + wr*64 + m*16 + ((lane>>4)<<2);
      int p = rm >> 7, bgi = (rm >> 4) & 7, rr = rm & 15;
      bf16x4 o;
      #pragma unroll
      for (int r=0;r<4;r++) o[r] = (bf16_t)(acc[m][n][r] + bvv);
      *(bf16x4*)(Cout + ((((size_t)p*8+bgi)*4+g)*1024 + col)*16 + rr) = o;
    }
  }
}

// ---------------- split GEMM: hi/lo A (two K-parts) x hi/lo B, 3 combos ----------------
template<int ACT_TANH, int OUT_PAIR>
__global__ __launch_bounds__(256) void gemm_split(
    const bf16_t* __restrict__ Ah1, const bf16_t* __restrict__ Al1,
    const bf16_t* __restrict__ Ah2, const bf16_t* __restrict__ Al2, int K1,
    const bf16_t* __restrict__ Bh, const bf16_t* __restrict__ Bl,
    float* __restrict__ Cf, bf16_t* __restrict__ Ch, bf16_t* __restrict__ Cl,
    int M, int N, int K, int nTN)
{
  __shared__ bf16_t sAh[128*64], sAl[128*64], sBh[128*64], sBl[128*64];
  int tid = threadIdx.x, lane = tid & 63, w = tid >> 6;
  int tm = blockIdx.x / nTN, tn = blockIdx.x % nTN;
  int row0 = tm*128, col0 = tn*128;
  int wr = w >> 1, wcc = w & 1;
  f32x4 acc[4][4] = {};
  for (int kt = 0; kt < K; kt += 64) {
    const bf16_t *Ah, *Al; int kl;
    if (kt < K1){ Ah=Ah1; Al=Al1; kl=kt; } else { Ah=Ah2; Al=Al2; kl=kt-K1; }
    __syncthreads();
    #pragma unroll
    for (int i=0;i<4;i++){
      int c = i*256 + tid;
      int r = c >> 3, kk = (c & 7) << 3;
      gll16(Ah + (size_t)(row0+r)*K1 + kl + kk, sAh + (size_t)(i*256 + w*64)*8);
      gll16(Al + (size_t)(row0+r)*K1 + kl + kk, sAl + (size_t)(i*256 + w*64)*8);
      gll16(Bh + (size_t)(col0+r)*K + kt + kk, sBh + (size_t)(i*256 + w*64)*8);
      gll16(Bl + (size_t)(col0+r)*K + kt + kk, sBl + (size_t)(i*256 + w*64)*8);
    }
    __syncthreads();
    #pragma unroll
    for (int kk=0;kk<64;kk+=32){
      bf16x8 avh[4], avl[4], bvh[4], bvl[4];
      #pragma unroll
      for (int m=0;m<4;m++){
        int off = (wr*64 + m*16 + (lane&15))*64 + kk + ((lane>>4)<<3);
        avh[m] = *(const bf16x8*)(sAh + off);
        avl[m] = *(const bf16x8*)(sAl + off);
      }
      #pragma unroll
      for (int n=0;n<4;n++){
        int off = (wcc*64 + n*16 + (lane&15))*64 + kk + ((lane>>4)<<3);
        bvh[n] = *(const bf16x8*)(sBh + off);
        bvl[n] = *(const bf16x8*)(sBl + off);
      }
      #pragma unroll
      for (int m=0;m<4;m++)
        #pragma unroll
        for (int n=0;n<4;n++){
          acc[m][n] = __builtin_amdgcn_mfma_f32_16x16x32_bf16(avh[m], bvh[n], acc[m][n], 0,0,0);
          acc[m][n] = __builtin_amdgcn_mfma_f32_16x16x32_bf16(avl[m], bvh[n], acc[m][n], 0,0,0);
          acc[m][n] = __builtin_amdgcn_mfma_f32_16x16x32_bf16(avh[m], bvl[n], acc[m][n], 0,0,0);
        }
    }
  }
  #pragma unroll
  for (int n=0;n<4;n++){
    int cn = col0 + wcc*64 + n*16 + (lane & 15);
    #pragma unroll
    for (int m=0;m<4;m++){
      int rm = row0 + wr*64 + m*16 + ((lane>>4)<<2);
      #pragma unroll
      for (int r=0;r<4;r++){
        float v = acc[m][n][r];
        if (ACT_TANH) v = tanhf(v);
        if (OUT_PAIR){
          bf16_t h = (bf16_t)v;
          Ch[(size_t)(rm+r)*N + cn] = h;
          Cl[(size_t)(rm+r)*N + cn] = (bf16_t)(v - (float)h);
        } else {
          Cf[(size_t)(rm+r)*N + cn] = v;
        }
      }
    }
  }
}

// ---------------- persistent LSTM loop ----------------
// 256 blocks (bg=bid>>5 batch-group of 16 rows, cg=bid&31 col-group of 32) x
// 512 thr. Per phase: stage h0[p-1] + h1[p-2] (hi/lo) into LDS via sc-bypass
// loads; unified K-loop (8 waves = 4 slot-groups x 2 K-halves); cells write h
// via sc write-through stores. Barrier: 16 relaxed agent sub-counters.
#define NBLK   256
#define WST    1032
#define AELEMS 16512          // 16*WST
#define SGF    2112           // 16*132 floats per region
#define LDS_BYTES 148992      // 4*AELEMS*2 + 2*SGF*4

__global__ __launch_bounds__(512, 2) void lstm_loop(
    const bf16_t* __restrict__ whh0, const bf16_t* __restrict__ wih1,
    const bf16_t* __restrict__ whh1, const bf16_t* __restrict__ x0gT,
    const float* __restrict__ bias1, const float* __restrict__ c0in,
    bf16_t* __restrict__ h0rh, bf16_t* __restrict__ h0rl,   // ring [2][128][1024]
    bf16_t* __restrict__ h1h,  bf16_t* __restrict__ h1l,    // hist [65][128][1024]
    float* __restrict__ outH, float* __restrict__ outC, int* bar)
{
  extern __shared__ char smem[];
  bf16_t* sH = (bf16_t*)smem;                 // h0h,h0l,h1h,h1l each AELEMS
  float*  sG = (float*)(smem + 4*AELEMS*2);   // 2 regions of SGF

  const int tid = threadIdx.x, lane = tid & 63, wv = tid >> 6;
  const int l15 = lane & 15, hi4 = lane >> 4, kg8 = hi4 << 3;
  const int bid = blockIdx.x, bg = bid >> 5, cg = bid & 31;
  const int kh = wv >> 2, sg = wv & 3;        // K-half, slot-group(=gate)
  const int row = tid >> 5, colp = tid & 31;  // cell mapping

  // weight row pointers (gate sg, cols cg*32 + l15 / +16+l15)
  const size_t wr0 = (size_t)(sg*1024 + cg*32 + l15)*1024 + kg8;
  const size_t wr1 = (size_t)(sg*1024 + cg*32 + 16 + l15)*1024 + kg8;
  const bf16_t* pw00 = whh0 + wr0; const bf16_t* pw01 = whh0 + wr1;
  const bf16_t* pw10 = wih1 + wr0; const bf16_t* pw11 = wih1 + wr1;
  const bf16_t* pw20 = whh1 + wr0; const bf16_t* pw21 = whh1 + wr1;
  const int aoff = l15*WST + kg8;

  const size_t cellg = (size_t)(bg*16 + row)*1024 + cg*32 + colp;
  float c0reg = c0in[cellg];
  float c1reg = c0in[131072 + cellg];
  float bs[4];
  #pragma unroll
  for (int g=0; g<4; ++g) bs[g] = bias1[(g<<10) + cg*32 + colp];

  for (int p = 0; p <= 64; ++p){
    // ---- stage h into LDS (sc-bypass reads of other blocks' wt stores) ----
    {
      const bf16_t* gsrc[4];
      gsrc[0] = h0rh + (size_t)(p & 1)*131072;
      gsrc[1] = h0rl + (size_t)(p & 1)*131072;
      gsrc[2] = h1h + (size_t)(p >= 1 ? p-1 : 0)*131072;
      gsrc[3] = h1l + (size_t)(p >= 1 ? p-1 : 0)*131072;
      bf16x8 tv[16];
      #pragma unroll
      for (int a=0;a<4;a++)
        #pragma unroll
        for (int it=0;it<4;it++){
          int c = it*512 + tid;
          tv[a*4+it] = ldg_sc(gsrc[a] + (size_t)(bg*16 + (c>>7))*1024 + ((c&127)<<3));
        }
      asm volatile("s_waitcnt vmcnt(0)" ::: "memory");
      __builtin_amdgcn_sched_barrier(0);
      #pragma unroll
      for (int a=0;a<4;a++)
        #pragma unroll
        for (int it=0;it<4;it++){
          int c = it*512 + tid;
          *(bf16x8*)(sH + a*AELEMS + (c>>7)*WST + ((c&127)<<3)) = tv[a*4+it];
        }
      __syncthreads();
    }

    // ---- hoist x0g reads (dense transposed layout) ----
    float xg[4] = {0,0,0,0};
    if (p < 64){
      #pragma unroll
      for (int g=0; g<4; ++g)
        xg[g] = (float)x0gT[((((size_t)p*8 + bg)*4 + g)*1024 + cg*32 + colp)*16 + row];
    }

    // ---- unified K-loop ----
    f32x4 accA0={}, accA1={}, accBi0={}, accBi1={}, accBh0={}, accBh1={};
    #pragma unroll
    for (int ks=0; ks<16; ++ks){
      const int K0 = kh*512 + ks*32;
      bf16x8 a0h = *(const bf16x8*)(sH + 0*AELEMS + aoff + K0);
      bf16x8 a0l = *(const bf16x8*)(sH + 1*AELEMS + aoff + K0);
      bf16x8 a1h = *(const bf16x8*)(sH + 2*AELEMS + aoff + K0);
      bf16x8 a1l = *(const bf16x8*)(sH + 3*AELEMS + aoff + K0);
      bf16x8 w00 = *(const bf16x8*)(pw00 + K0);
      bf16x8 w01 = *(const bf16x8*)(pw01 + K0);
      bf16x8 w10 = *(const bf16x8*)(pw10 + K0);
      bf16x8 w11 = *(const bf16x8*)(pw11 + K0);
      bf16x8 w20 = *(const bf16x8*)(pw20 + K0);
      bf16x8 w21 = *(const bf16x8*)(pw21 + K0);
      MFMA16(accA0, a0h, w00); MFMA16(accA0, a0l, w00);
      MFMA16(accA1, a0h, w01); MFMA16(accA1, a0l, w01);
      MFMA16(accBi0, a0h, w10); MFMA16(accBi0, a0l, w10);
      MFMA16(accBi1, a0h, w11); MFMA16(accBi1, a0l, w11);
      MFMA16(accBh0, a1h, w20); MFMA16(accBh0, a1l, w20);
      MFMA16(accBh1, a1h, w21); MFMA16(accBh1, a1l, w21);
    }

    // ---- layer-0 gates -> sG, cell A ----
    #pragma unroll
    for (int r=0;r<4;r++){
      sG[kh*SGF + (hi4*4+r)*132 + sg*32 + l15]      = accA0[r];
      sG[kh*SGF + (hi4*4+r)*132 + sg*32 + 16 + l15] = accA1[r];
    }
    __syncthreads();
    if (p < 64){
      float gv[4];
      #pragma unroll
      for (int g=0; g<4; ++g)
        gv[g] = sG[row*132 + g*32 + colp] + sG[SGF + row*132 + g*32 + colp] + xg[g];
      float cv = sigm(gv[1])*c0reg + sigm(gv[0])*tanhf(gv[2]);
      float hv = sigm(gv[3])*tanhf(cv);
      c0reg = cv;
      bf16_t hh = (bf16_t)hv;
      bf16_t hl = (bf16_t)(hv - (float)hh);
      bf16_t* dh = h0rh + (size_t)((p+1)&1)*131072 + cellg;
      bf16_t* dl = h0rl + (size_t)((p+1)&1)*131072 + cellg;
      stg_sc(dh, hh); stg_sc(dl, hl);
      if (p == 63){ outH[cellg] = hv; outC[cellg] = cv; }
    }
    __syncthreads();

    // ---- layer-1 gates -> sG, cell B ----
    #pragma unroll
    for (int r=0;r<4;r++){
      sG[kh*SGF + (hi4*4+r)*132 + sg*32 + l15]      = accBi0[r] + accBh0[r];
      sG[kh*SGF + (hi4*4+r)*132 + sg*32 + 16 + l15] = accBi1[r] + accBh1[r];
    }
    __syncthreads();
    if (p >= 1){
      float gv[4];
      #pragma unroll
      for (int g=0; g<4; ++g)
        gv[g] = sG[row*132 + g*32 + colp] + sG[SGF + row*132 + g*32 + colp] + bs[g];
      float cv = sigm(gv[1])*c1reg + sigm(gv[0])*tanhf(gv[2]);
      float hv = sigm(gv[3])*tanhf(cv);
      c1reg = cv;
      bf16_t hh = (bf16_t)hv;
      bf16_t hl = (bf16_t)(hv - (float)hh);
      stg_sc(h1h + (size_t)p*131072 + cellg, hh);
      stg_sc(h1l + (size_t)p*131072 + cellg, hl);
      if (p == 64){ outH[131072 + cellg] = hv; outC[131072 + cellg] = cv; }
    }

    // ---- grid barrier (no fences; 16 spread sub-counters) ----
    if (p < 64){
      __syncthreads();   // drains each wave's vmem (incl. sc stores)
      if (tid == 0){
        __hip_atomic_fetch_add(bar + (bid & 15)*64, 1, __ATOMIC_RELAXED, __HIP_MEMORY_SCOPE_AGENT);
        const int tgt = NBLK*(p+1);
        for(;;){
          int s = 0;
          #pragma unroll
          for (int i=0;i<16;i++)
            s += __hip_atomic_load(bar + i*64, __ATOMIC_RELAXED, __HIP_MEMORY_SCOPE_AGENT);
          if (s >= tgt) break;
          __builtin_amdgcn_s_sleep(2);
        }
      }
      __syncthreads();
      __builtin_amdgcn_sched_barrier(0);
    }
  }
}

// ---------------- scores + softmax (per batch row b), post-loop ----------------
__global__ __launch_bounds__(256) void attn_sm(
    const bf16_t* __restrict__ h1h, const bf16_t* __restrict__ h1l,
    const bf16_t* __restrict__ cwh, const bf16_t* __restrict__ cwl,
    float* __restrict__ a_all, float* __restrict__ outA)
{
  __shared__ bf16_t sAh[64*64], sAl[64*64];
  __shared__ bf16_t sBh[128*64], sBl[128*64];
  __shared__ float sS[64*128];
  int b = blockIdx.x;
  int tid = threadIdx.x, lane = tid&63, w = tid>>6;
  int wr = w>>1, wcc = w&1;
  f32x4 acc[2][4] = {};
  for (int kt=0; kt<1024; kt+=64){
    __syncthreads();
    #pragma unroll
    for (int i=0;i<2;i++){
      int c = i*256+tid; int r = c>>3, kk=(c&7)<<3;
      size_t src = (size_t)(r+1)*131072 + (size_t)b*1024 + kt+kk;
      gll16(h1h + src, sAh + (size_t)(i*256 + w*64)*8);
      gll16(h1l + src, sAl + (size_t)(i*256 + w*64)*8);
    }
    #pragma unroll
    for (int i=0;i<4;i++){
      int c = i*256+tid; int br=c>>3, kk=(c&7)<<3;
      size_t src = ((size_t)b*128 + br)*1024 + kt+kk;
      gll16(cwh + src, sBh + (size_t)(i*256+w*64)*8);
      gll16(cwl + src, sBl + (size_t)(i*256+w*64)*8);
    }
    __syncthreads();
    #pragma unroll
    for (int kk=0;kk<64;kk+=32){
      bf16x8 avh[2], avl[2], bvh[4], bvl[4];
      #pragma unroll
      for (int m=0;m<2;m++){
        int off = (wr*32 + m*16 + (lane&15))*64 + kk + ((lane>>4)<<3);
        avh[m] = *(const bf16x8*)(sAh + off);
        avl[m] = *(const bf16x8*)(sAl + off);
      }
      #pragma unroll
      for (int n=0;n<4;n++){
        int off = (wcc*64 + n*16 + (lane&15))*64 + kk + ((lane>>4)<<3);
        bvh[n] = *(const bf16x8*)(sBh + off);
        bvl[n] = *(const bf16x8*)(sBl + off);
      }
      #pragma unroll
      for (int m=0;m<2;m++)
        #pragma unroll
        for (int n=0;n<4;n++){
          acc[m][n] = __builtin_amdgcn_mfma_f32_16x16x32_bf16(avh[m], bvh[n], acc[m][n], 0,0,0);
          acc[m][n] = __builtin_amdgcn_mfma_f32_16x16x32_bf16(avl[m], bvh[n], acc[m][n], 0,0,0);
          acc[m][n] = __builtin_amdgcn_mfma_f32_16x16x32_bf16(avh[m], bvl[n], acc[m][n], 0,0,0);
        }
    }
  }
  #pragma unroll
  for (int m=0;m<2;m++)
    #pragma unroll
    for (int n=0;n<4;n++)
      #pragma unroll
      for (int r=0;r<4;r++){
        int trow = wr*32 + m*16 + ((lane>>4)<<2) + r;
        int tc   = wcc*64 + n*16 + (lane&15);
        sS[trow*128+tc] = acc[m][n][r];
      }
  __syncthreads();
  for (int i=0;i<16;i++){
    int r = w*16 + i;
    float v0 = sS[r*128 + lane], v1 = sS[r*128 + 64 + lane];
    float mx = fmaxf(v0, v1);
    #pragma unroll
    for (int off=32; off; off>>=1) mx = fmaxf(mx, __shfl_xor(mx, off));
    float e0 = expf(v0-mx), e1 = expf(v1-mx);
    float sm = e0+e1;
    #pragma unroll
    for (int off=32; off; off>>=1) sm += __shfl_xor(sm, off);
    float inv = 1.f/sm;
    size_t base = ((size_t)r*128 + b)*128;
    a_all[base + lane]      = e0*inv;
    a_all[base + 64 + lane] = e1*inv;
    if (r == 63){
      outA[(size_t)b*128 + lane]      = e0*inv;
      outA[(size_t)b*128 + 64 + lane] = e1*inv;
    }
  }
}

// ---------------- wc (fp32 VALU): wc[t,b,:] = sum_s a[t,b,s]*ctx[b,s,:] ----
__global__ __launch_bounds__(256) void wc_all(
    const float* __restrict__ a_all, const float* __restrict__ ctx,
    bf16_t* __restrict__ wch, bf16_t* __restrict__ wcl)
{
  int bid = blockIdx.x;
  int b = bid & 127, tg = bid >> 7;  // tg 0..3, 16 t each
  int tid = threadIdx.x;
  __shared__ float sa[16][128];
  int t0 = tg*16;
  #pragma unroll
  for (int i=0;i<8;i++){
    int q = i*256 + tid;
    int ti = q >> 7, s = q & 127;
    sa[ti][s] = a_all[((size_t)(t0+ti)*128 + b)*128 + s];
  }
  __syncthreads();
  f32x4 acc[16];
  #pragma unroll
  for (int i=0;i<16;i++) acc[i] = f32x4{0,0,0,0};
  const float* cb = ctx + (size_t)b*128*1024 + tid*4;
  for (int s=0;s<128;s++){
    f32x4 c = *(const f32x4*)(cb + (size_t)s*1024);
    #pragma unroll
    for (int ti=0;ti<16;ti++){
      float av = sa[ti][s];
      acc[ti] += av * c;
    }
  }
  #pragma unroll
  for (int ti=0;ti<16;ti++){
    size_t m = (size_t)(t0+ti)*128 + b;
    bf16x4 h, l;
    #pragma unroll
    for (int j=0;j<4;j++){
      float v = acc[ti][j];
      h[j] = (bf16_t)v; l[j] = (bf16_t)(v - (float)h[j]);
    }
    *(bf16x4*)(wch + m*1024 + tid*4) = h;
    *(bf16x4*)(wcl + m*1024 + tid*4) = l;
  }
}

// ---------------- host ----------------
extern "C" void kernel_launch(void* const* d_in, const int* in_sizes, int n_in,
                              void* d_out, int out_size, void* d_ws, size_t ws_size,
                              hipStream_t stream)
{
  (void)in_sizes; (void)n_in; (void)out_size; (void)ws_size;
  const int TT=64, BB=128, H=1024, G=4096, BH=128*1024;

  const int*   tok  = (const int*)d_in[0];
  const float* h0   = (const float*)d_in[1];
  const float* c0   = (const float*)d_in[2];
  const float* ctx  = (const float*)d_in[3];
  const float* embW = (const float*)d_in[5];
  const float* wih  = (const float*)d_in[6];
  const float* whh  = (const float*)d_in[7];
  const float* bih  = (const float*)d_in[8];
  const float* bhh  = (const float*)d_in[9];
  const float* Win  = (const float*)d_in[10];
  const float* Wout = (const float*)d_in[11];

  float* outY = (float*)d_out;                      // [T,B,H]
  float* outH = outY + (size_t)TT*BB*H;             // [2,B,H]
  float* outC = outH + (size_t)2*BH;                // [2,B,H]
  float* outA = outC + (size_t)2*BH;                // [B,S]

  char* ws = (char*)d_ws;
  size_t o = 0;
  auto carve = [&](size_t bytes)->char* {
    char* p = ws + o; o += (bytes + 255) & ~(size_t)255; return p;
  };
  bf16_t* wihB  = (bf16_t*)carve((size_t)2*G*H*2);       // 16MB
  bf16_t* whhB  = (bf16_t*)carve((size_t)2*G*H*2);       // 16MB
  bf16_t* woutH = (bf16_t*)carve((size_t)H*2*H*2);       // 4MB
  bf16_t* woutL = (bf16_t*)carve((size_t)H*2*H*2);       // 4MB
  bf16_t* winTh = (bf16_t*)carve((size_t)H*H*2);         // 2MB
  bf16_t* winTl = (bf16_t*)carve((size_t)H*H*2);         // 2MB
  bf16_t* ctxh  = (bf16_t*)carve((size_t)BB*128*H*2);    // 32MB (post-loop: wch)
  bf16_t* ctxl  = (bf16_t*)carve((size_t)BB*128*H*2);    // 32MB (post-loop: wcl)
  bf16_t* cwh   = (bf16_t*)carve((size_t)BB*128*H*2);    // 32MB (pre: xemb overlays)
  bf16_t* cwl   = (bf16_t*)carve((size_t)BB*128*H*2);    // 32MB
  bf16_t* x0gT  = (bf16_t*)carve((size_t)TT*BB*G*2);     // 64MB
  bf16_t* h0rh  = (bf16_t*)carve((size_t)2*BH*2);        // ring, 2 slots
  bf16_t* h0rl  = (bf16_t*)carve((size_t)2*BH*2);
  bf16_t* h1h   = (bf16_t*)carve((size_t)(TT+1)*BH*2);   // 17MB history
  bf16_t* h1l   = (bf16_t*)carve((size_t)(TT+1)*BH*2);   // 17MB
  float*  a_all = (float*)carve((size_t)TT*BB*128*4);    // 4MB
  float*  biasF = (float*)carve((size_t)2*G*4);
  int*    bar   = (int*)carve(16*64*4);

  bf16_t* xemb = cwh;            // overlays ctxW-hi (dead until ctxW GEMM)
  bf16_t* wch  = ctxh;           // overlays ctx pair (dead post-loop)
  bf16_t* wcl  = ctxl;

  // ---- prep ----
  hipMemsetAsync(bar, 0, 16*64*4, stream);
  f2b<<<(2*G*H)/1024, 256, 0, stream>>>(wih, wihB, 2*G*H);
  f2b<<<(2*G*H)/1024, 256, 0, stream>>>(whh, whhB, 2*G*H);
  f2b_pair<<<(H*2*H)/1024, 256, 0, stream>>>(Wout, woutH, woutL, H*2*H);
  f2b_pair<<<(BB*128*H)/1024, 256, 0, stream>>>(ctx, ctxh, ctxl, BB*128*H);
  f2b_pair<<<BH/1024, 256, 0, stream>>>(h0, h0rh, h0rl, BH);
  f2b_pair<<<BH/1024, 256, 0, stream>>>(h0 + BH, h1h, h1l, BH);
  transWin<<<1024, 256, 0, stream>>>(Win, winTh, winTl);
  bias_combine<<<(2*G)/256, 256, 0, stream>>>(bih, bhh, biasF, 2*G);
  embed_gather<<<TT*BB, 256, 0, stream>>>(tok, embW, xemb);

  // ---- one-time GEMMs ----
  gemm_bt<<<(TT*BB/128)*(G/128), 256, 0, stream>>>(xemb, wihB, biasF, x0gT, TT*BB, G, H, G/128);
  gemm_split<0,1><<<(BB*128/128)*(H/128), 256, 0, stream>>>(
      ctxh, ctxl, ctxh, ctxl, H, winTh, winTl,
      nullptr, cwh, cwl, BB*128, H, H, H/128);

  // ---- persistent recurrence ----
  hipFuncSetAttribute((const void*)lstm_loop,
                      hipFuncAttributeMaxDynamicSharedMemorySize, LDS_BYTES);
  lstm_loop<<<NBLK, 512, LDS_BYTES, stream>>>(
      whhB, wihB + (size_t)G*H, whhB + (size_t)G*H, x0gT, biasF + G, c0,
      h0rh, h0rl, h1h, h1l, outH, outC, bar);

  // ---- post-loop attention ----
  attn_sm<<<BB, 256, 0, stream>>>(h1h, h1l, cwh, cwl, a_all, outA);
  wc_all<<<BB*4, 256, 0, stream>>>(a_all, ctx, wch, wcl);

  gemm_split<1,0><<<(TT*BB/128)*(H/128), 256, 0, stream>>>(
      wch, wcl, h1h + BH, h1l + BH, H, woutH, woutL,
      outY, nullptr, nullptr, TT*BB, H, 2*H, H/128);
}

// Round 8
// 2317.045 us; speedup vs baseline: 2.0668x; 1.0156x over previous
//
#include <hip/hip_runtime.h>
#include <hip/hip_bf16.h>
#include <stdint.h>

// Decoder: 2-layer LSTM + Luong attention. input_feed=0 => attention deferred
// post-loop. R8 = R5 skeleton with CACHEABLE staging reads (L2 dedup across
// same-XCD blocks) + h0 as 65-slot history (unique address per phase => no
// stale-line hazard) + one entry threadfence (kills cross-replay staleness).
// h writes stay sc0sc1 write-through (visible at L3 for other XCDs' misses).

typedef __bf16 bf16_t;
typedef __bf16 bf16x8 __attribute__((ext_vector_type(8)));
typedef __bf16 bf16x4 __attribute__((ext_vector_type(4)));
typedef float f32x4 __attribute__((ext_vector_type(4)));

#define AS1 __attribute__((address_space(1)))
#define AS3 __attribute__((address_space(3)))

__device__ __forceinline__ void gll16(const bf16_t* g, bf16_t* l) {
  __builtin_amdgcn_global_load_lds((const AS1 void*)g, (AS3 void*)l, 16, 0, 0);
}

__device__ __forceinline__ float sigm(float x){ return 1.f/(1.f+expf(-x)); }

#define MFMA16(acc, a, b) acc = __builtin_amdgcn_mfma_f32_16x16x32_bf16(a, b, acc, 0,0,0)

// write-through coherent store (proven in R5)
__device__ __forceinline__ void stg_sc(bf16_t* p, bf16_t v){
  uint32_t w = (uint32_t)__builtin_bit_cast(uint16_t, v);
  asm volatile("global_store_short %0, %1, off sc0 sc1" :: "v"(p), "v"(w) : "memory");
}

// ---------------- prep kernels ----------------
__global__ void f2b(const float* __restrict__ in, bf16_t* __restrict__ outp, int n){
  int i = (blockIdx.x*256 + threadIdx.x)*4;
  if (i >= n) return;
  float4 v = *(const float4*)(in + i);
  bf16x4 o; o[0]=(bf16_t)v.x; o[1]=(bf16_t)v.y; o[2]=(bf16_t)v.z; o[3]=(bf16_t)v.w;
  *(bf16x4*)(outp + i) = o;
}

__global__ void f2b_pair(const float* __restrict__ in, bf16_t* __restrict__ oh,
                         bf16_t* __restrict__ ol, int n){
  int i = (blockIdx.x*256 + threadIdx.x)*4;
  if (i >= n) return;
  float4 v = *(const float4*)(in + i);
  float vv[4] = {v.x, v.y, v.z, v.w};
  bf16x4 h, l;
  #pragma unroll
  for (int j=0;j<4;j++){ h[j]=(bf16_t)vv[j]; l[j]=(bf16_t)(vv[j]-(float)h[j]); }
  *(bf16x4*)(oh + i) = h;
  *(bf16x4*)(ol + i) = l;
}

__global__ void bias_combine(const float* __restrict__ a, const float* __restrict__ b,
                             float* __restrict__ o, int n){
  int i = blockIdx.x*256 + threadIdx.x;
  if (i < n) o[i] = a[i] + b[i];
}

__global__ void embed_gather(const int* __restrict__ tokp, const float* __restrict__ embW,
                             bf16_t* __restrict__ xe){
  int m = blockIdx.x;
  int tokv = tokp[m];
  const float* src = embW + (size_t)tokv*1024 + threadIdx.x*4;
  float4 v = *(const float4*)src;
  bf16x4 o; o[0]=(bf16_t)v.x; o[1]=(bf16_t)v.y; o[2]=(bf16_t)v.z; o[3]=(bf16_t)v.w;
  *(bf16x4*)(xe + (size_t)m*1024 + threadIdx.x*4) = o;
}

// winT[e,d] = split(Win[d,e])
__global__ void transWin(const float* __restrict__ in, bf16_t* __restrict__ oh,
                         bf16_t* __restrict__ ol){
  __shared__ float t[32][33];
  int bi = blockIdx.x & 31, bj = blockIdx.x >> 5;
  int tx = threadIdx.x & 31, ty = threadIdx.x >> 5;  // 32 x 8
  #pragma unroll
  for (int i=0;i<4;i++){
    int d = bi*32 + ty + i*8, e = bj*32 + tx;
    t[ty+i*8][tx] = in[(size_t)d*1024 + e];
  }
  __syncthreads();
  #pragma unroll
  for (int i=0;i<4;i++){
    int e = bj*32 + ty + i*8, d = bi*32 + tx;
    float v = t[tx][ty+i*8];
    bf16_t h = (bf16_t)v;
    oh[(size_t)e*1024 + d] = h;
    ol[(size_t)e*1024 + d] = (bf16_t)(v - (float)h);
  }
}

// -------- x0g GEMM: x0gT[t][bg][g][col][16 rows] = xemb@wih0^T + bias0 --------
__global__ __launch_bounds__(256) void gemm_bt(
    const bf16_t* __restrict__ A, const bf16_t* __restrict__ Bm,
    const float* __restrict__ bias, bf16_t* __restrict__ Cout,
    int M, int N, int K, int nTN)
{
  __shared__ bf16_t sA[128*64];
  __shared__ bf16_t sB[128*64];
  int tid = threadIdx.x, lane = tid & 63, w = tid >> 6;
  int tm = blockIdx.x / nTN, tn = blockIdx.x % nTN;
  int row0 = tm*128, col0 = tn*128;
  int wr = w >> 1, wcc = w & 1;
  f32x4 acc[4][4] = {};
  for (int kt = 0; kt < K; kt += 64) {
    __syncthreads();
    #pragma unroll
    for (int i=0;i<4;i++){
      int c = i*256 + tid;
      int r = c >> 3, kk = (c & 7) << 3;
      gll16(A  + (size_t)(row0+r)*K + kt + kk, sA + (size_t)(i*256 + w*64)*8);
      gll16(Bm + (size_t)(col0+r)*K + kt + kk, sB + (size_t)(i*256 + w*64)*8);
    }
    __syncthreads();
    #pragma unroll
    for (int kk=0;kk<64;kk+=32){
      bf16x8 av[4], bv[4];
      #pragma unroll
      for (int m=0;m<4;m++) av[m] = *(const bf16x8*)(sA + (wr*64 + m*16 + (lane&15))*64 + kk + ((lane>>4)<<3));
      #pragma unroll
      for (int n=0;n<4;n++) bv[n] = *(const bf16x8*)(sB + (wcc*64 + n*16 + (lane&15))*64 + kk + ((lane>>4)<<3));
      #pragma unroll
      for (int m=0;m<4;m++)
        #pragma unroll
        for (int n=0;n<4;n++)
          acc[m][n] = __builtin_amdgcn_mfma_f32_16x16x32_bf16(av[m], bv[n], acc[m][n], 0,0,0);
    }
  }
  #pragma unroll
  for (int n=0;n<4;n++){
    int cn = col0 + wcc*64 + n*16 + (lane & 15);
    float bvv = bias[cn];
    int g = cn >> 10, col = cn & 1023;
    #pragma unroll
    for (int m=0;m<4;m++){
      int rm = row0 + wr*64 + m*16 + ((lane>>4)<<2);
      int p = rm >> 7, bgi = (rm >> 4) & 7, rr = rm & 15;
      bf16x4 o;
      #pragma unroll
      for (int r=0;r<4;r++) o[r] = (bf16_t)(acc[m][n][r] + bvv);
      *(bf16x4*)(Cout + ((((size_t)p*8+bgi)*4+g)*1024 + col)*16 + rr) = o;
    }
  }
}

// ---------------- split GEMM: hi/lo A (two K-parts) x hi/lo B, 3 combos ----------------
template<int ACT_TANH, int OUT_PAIR>
__global__ __launch_bounds__(256) void gemm_split(
    const bf16_t* __restrict__ Ah1, const bf16_t* __restrict__ Al1,
    const bf16_t* __restrict__ Ah2, const bf16_t* __restrict__ Al2, int K1,
    const bf16_t* __restrict__ Bh, const bf16_t* __restrict__ Bl,
    float* __restrict__ Cf, bf16_t* __restrict__ Ch, bf16_t* __restrict__ Cl,
    int M, int N, int K, int nTN)
{
  __shared__ bf16_t sAh[128*64], sAl[128*64], sBh[128*64], sBl[128*64];
  int tid = threadIdx.x, lane = tid & 63, w = tid >> 6;
  int tm = blockIdx.x / nTN, tn = blockIdx.x % nTN;
  int row0 = tm*128, col0 = tn*128;
  int wr = w >> 1, wcc = w & 1;
  f32x4 acc[4][4] = {};
  for (int kt = 0; kt < K; kt += 64) {
    const bf16_t *Ah, *Al; int kl;
    if (kt < K1){ Ah=Ah1; Al=Al1; kl=kt; } else { Ah=Ah2; Al=Al2; kl=kt-K1; }
    __syncthreads();
    #pragma unroll
    for (int i=0;i<4;i++){
      int c = i*256 + tid;
      int r = c >> 3, kk = (c & 7) << 3;
      gll16(Ah + (size_t)(row0+r)*K1 + kl + kk, sAh + (size_t)(i*256 + w*64)*8);
      gll16(Al + (size_t)(row0+r)*K1 + kl + kk, sAl + (size_t)(i*256 + w*64)*8);
      gll16(Bh + (size_t)(col0+r)*K + kt + kk, sBh + (size_t)(i*256 + w*64)*8);
      gll16(Bl + (size_t)(col0+r)*K + kt + kk, sBl + (size_t)(i*256 + w*64)*8);
    }
    __syncthreads();
    #pragma unroll
    for (int kk=0;kk<64;kk+=32){
      bf16x8 avh[4], avl[4], bvh[4], bvl[4];
      #pragma unroll
      for (int m=0;m<4;m++){
        int off = (wr*64 + m*16 + (lane&15))*64 + kk + ((lane>>4)<<3);
        avh[m] = *(const bf16x8*)(sAh + off);
        avl[m] = *(const bf16x8*)(sAl + off);
      }
      #pragma unroll
      for (int n=0;n<4;n++){
        int off = (wcc*64 + n*16 + (lane&15))*64 + kk + ((lane>>4)<<3);
        bvh[n] = *(const bf16x8*)(sBh + off);
        bvl[n] = *(const bf16x8*)(sBl + off);
      }
      #pragma unroll
      for (int m=0;m<4;m++)
        #pragma unroll
        for (int n=0;n<4;n++){
          acc[m][n] = __builtin_amdgcn_mfma_f32_16x16x32_bf16(avh[m], bvh[n], acc[m][n], 0,0,0);
          acc[m][n] = __builtin_amdgcn_mfma_f32_16x16x32_bf16(avl[m], bvh[n], acc[m][n], 0,0,0);
          acc[m][n] = __builtin_amdgcn_mfma_f32_16x16x32_bf16(avh[m], bvl[n], acc[m][n], 0,0,0);
        }
    }
  }
  #pragma unroll
  for (int n=0;n<4;n++){
    int cn = col0 + wcc*64 + n*16 + (lane & 15);
    #pragma unroll
    for (int m=0;m<4;m++){
      int rm = row0 + wr*64 + m*16 + ((lane>>4)<<2);
      #pragma unroll
      for (int r=0;r<4;r++){
        float v = acc[m][n][r];
        if (ACT_TANH) v = tanhf(v);
        if (OUT_PAIR){
          bf16_t h = (bf16_t)v;
          Ch[(size_t)(rm+r)*N + cn] = h;
          Cl[(size_t)(rm+r)*N + cn] = (bf16_t)(v - (float)h);
        } else {
          Cf[(size_t)(rm+r)*N + cn] = v;
        }
      }
    }
  }
}

// ---------------- persistent LSTM loop (R5 skeleton, cacheable staging) ----------------
#define NBLK   256
#define WST    1032
#define AELEMS 16512          // 16*WST
#define SGF    2112           // 16*132 floats per region
#define LDS_BYTES 148992      // 4*AELEMS*2 + 2*SGF*4

__global__ __launch_bounds__(512, 2) void lstm_loop(
    const bf16_t* __restrict__ whh0, const bf16_t* __restrict__ wih1,
    const bf16_t* __restrict__ whh1, const bf16_t* __restrict__ x0gT,
    const float* __restrict__ bias1, const float* __restrict__ c0in,
    bf16_t* __restrict__ h0h, bf16_t* __restrict__ h0l,     // hist [65][128][1024]
    bf16_t* __restrict__ h1h, bf16_t* __restrict__ h1l,     // hist [65][128][1024]
    float* __restrict__ outH, float* __restrict__ outC, int* bar)
{
  extern __shared__ char smem[];
  bf16_t* sH = (bf16_t*)smem;                 // h0h,h0l,h1h,h1l each AELEMS
  float*  sG = (float*)(smem + 4*AELEMS*2);   // 2 regions of SGF

  // one-time acquire: invalidate any stale L1/L2 lines (poison / prior replay)
  __threadfence();

  const int tid = threadIdx.x, lane = tid & 63, wv = tid >> 6;
  const int l15 = lane & 15, hi4 = lane >> 4, kg8 = hi4 << 3;
  const int bid = blockIdx.x, bg = bid >> 5, cg = bid & 31;
  const int kh = wv >> 2, sg = wv & 3;        // K-half, slot-group(=gate)
  const int row = tid >> 5, colp = tid & 31;  // cell mapping

  // weight row pointers (gate sg, cols cg*32 + l15 / +16+l15)
  const size_t wr0 = (size_t)(sg*1024 + cg*32 + l15)*1024 + kg8;
  const size_t wr1 = (size_t)(sg*1024 + cg*32 + 16 + l15)*1024 + kg8;
  const bf16_t* pw00 = whh0 + wr0; const bf16_t* pw01 = whh0 + wr1;
  const bf16_t* pw10 = wih1 + wr0; const bf16_t* pw11 = wih1 + wr1;
  const bf16_t* pw20 = whh1 + wr0; const bf16_t* pw21 = whh1 + wr1;
  const int aoff = l15*WST + kg8;

  const size_t cellg = (size_t)(bg*16 + row)*1024 + cg*32 + colp;
  float c0reg = c0in[cellg];
  float c1reg = c0in[131072 + cellg];
  float bs[4];
  #pragma unroll
  for (int g=0; g<4; ++g) bs[g] = bias1[(g<<10) + cg*32 + colp];

  for (int p = 0; p <= 64; ++p){
    // ---- stage h into LDS (cacheable reads; unique slot per phase) ----
    {
      const bf16_t* gsrc[4];
      gsrc[0] = h0h + (size_t)p*131072;
      gsrc[1] = h0l + (size_t)p*131072;
      gsrc[2] = h1h + (size_t)(p >= 1 ? p-1 : 0)*131072;
      gsrc[3] = h1l + (size_t)(p >= 1 ? p-1 : 0)*131072;
      bf16x8 tv[16];
      #pragma unroll
      for (int a=0;a<4;a++)
        #pragma unroll
        for (int it=0;it<4;it++){
          int c = it*512 + tid;
          tv[a*4+it] = *(const bf16x8*)(gsrc[a] + (size_t)(bg*16 + (c>>7))*1024 + ((c&127)<<3));
        }
      #pragma unroll
      for (int a=0;a<4;a++)
        #pragma unroll
        for (int it=0;it<4;it++){
          int c = it*512 + tid;
          *(bf16x8*)(sH + a*AELEMS + (c>>7)*WST + ((c&127)<<3)) = tv[a*4+it];
        }
      __syncthreads();
    }

    // ---- hoist x0g reads (dense transposed layout, cacheable) ----
    float xg[4] = {0,0,0,0};
    if (p < 64){
      #pragma unroll
      for (int g=0; g<4; ++g)
        xg[g] = (float)x0gT[((((size_t)p*8 + bg)*4 + g)*1024 + cg*32 + colp)*16 + row];
    }

    // ---- unified K-loop ----
    f32x4 accA0={}, accA1={}, accBi0={}, accBi1={}, accBh0={}, accBh1={};
    #pragma unroll
    for (int ks=0; ks<16; ++ks){
      const int K0 = kh*512 + ks*32;
      bf16x8 a0h = *(const bf16x8*)(sH + 0*AELEMS + aoff + K0);
      bf16x8 a0l = *(const bf16x8*)(sH + 1*AELEMS + aoff + K0);
      bf16x8 a1h = *(const bf16x8*)(sH + 2*AELEMS + aoff + K0);
      bf16x8 a1l = *(const bf16x8*)(sH + 3*AELEMS + aoff + K0);
      bf16x8 w00 = *(const bf16x8*)(pw00 + K0);
      bf16x8 w01 = *(const bf16x8*)(pw01 + K0);
      bf16x8 w10 = *(const bf16x8*)(pw10 + K0);
      bf16x8 w11 = *(const bf16x8*)(pw11 + K0);
      bf16x8 w20 = *(const bf16x8*)(pw20 + K0);
      bf16x8 w21 = *(const bf16x8*)(pw21 + K0);
      MFMA16(accA0, a0h, w00); MFMA16(accA0, a0l, w00);
      MFMA16(accA1, a0h, w01); MFMA16(accA1, a0l, w01);
      MFMA16(accBi0, a0h, w10); MFMA16(accBi0, a0l, w10);
      MFMA16(accBi1, a0h, w11); MFMA16(accBi1, a0l, w11);
      MFMA16(accBh0, a1h, w20); MFMA16(accBh0, a1l, w20);
      MFMA16(accBh1, a1h, w21); MFMA16(accBh1, a1l, w21);
    }

    // ---- layer-0 gates -> sG, cell A ----
    #pragma unroll
    for (int r=0;r<4;r++){
      sG[kh*SGF + (hi4*4+r)*132 + sg*32 + l15]      = accA0[r];
      sG[kh*SGF + (hi4*4+r)*132 + sg*32 + 16 + l15] = accA1[r];
    }
    __syncthreads();
    if (p < 64){
      float gv[4];
      #pragma unroll
      for (int g=0; g<4; ++g)
        gv[g] = sG[row*132 + g*32 + colp] + sG[SGF + row*132 + g*32 + colp] + xg[g];
      float cv = sigm(gv[1])*c0reg + sigm(gv[0])*tanhf(gv[2]);
      float hv = sigm(gv[3])*tanhf(cv);
      c0reg = cv;
      bf16_t hh = (bf16_t)hv;
      bf16_t hl = (bf16_t)(hv - (float)hh);
      stg_sc(h0h + (size_t)(p+1)*131072 + cellg, hh);
      stg_sc(h0l + (size_t)(p+1)*131072 + cellg, hl);
      if (p == 63){ outH[cellg] = hv; outC[cellg] = cv; }
    }
    __syncthreads();

    // ---- layer-1 gates -> sG, cell B ----
    #pragma unroll
    for (int r=0;r<4;r++){
      sG[kh*SGF + (hi4*4+r)*132 + sg*32 + l15]      = accBi0[r] + accBh0[r];
      sG[kh*SGF + (hi4*4+r)*132 + sg*32 + 16 + l15] = accBi1[r] + accBh1[r];
    }
    __syncthreads();
    if (p >= 1){
      float gv[4];
      #pragma unroll
      for (int g=0; g<4; ++g)
        gv[g] = sG[row*132 + g*32 + colp] + sG[SGF + row*132 + g*32 + colp] + bs[g];
      float cv = sigm(gv[1])*c1reg + sigm(gv[0])*tanhf(gv[2]);
      float hv = sigm(gv[3])*tanhf(cv);
      c1reg = cv;
      bf16_t hh = (bf16_t)hv;
      bf16_t hl = (bf16_t)(hv - (float)hh);
      stg_sc(h1h + (size_t)p*131072 + cellg, hh);
      stg_sc(h1l + (size_t)p*131072 + cellg, hl);
      if (p == 64){ outH[131072 + cellg] = hv; outC[131072 + cellg] = cv; }
    }

    // ---- grid barrier (fence-free; 16 spread sub-counters) ----
    if (p < 64){
      __syncthreads();   // drains each wave's vmem (incl. sc stores)
      if (tid == 0){
        __hip_atomic_fetch_add(bar + (bid & 15)*64, 1, __ATOMIC_RELAXED, __HIP_MEMORY_SCOPE_AGENT);
        const int tgt = NBLK*(p+1);
        for(;;){
          int s = 0;
          #pragma unroll
          for (int i=0;i<16;i++)
            s += __hip_atomic_load(bar + i*64, __ATOMIC_RELAXED, __HIP_MEMORY_SCOPE_AGENT);
          if (s >= tgt) break;
          __builtin_amdgcn_s_sleep(2);
        }
      }
      __syncthreads();
      asm volatile("" ::: "memory");          // no load hoisting above the spin
      __builtin_amdgcn_sched_barrier(0);
    }
  }
}

// ---------------- scores + softmax (per batch row b), post-loop ----------------
__global__ __launch_bounds__(256) void attn_sm(
    const bf16_t* __restrict__ h1h, const bf16_t* __restrict__ h1l,
    const bf16_t* __restrict__ cwh, const bf16_t* __restrict__ cwl,
    float* __restrict__ a_all, float* __restrict__ outA)
{
  __shared__ bf16_t sAh[64*64], sAl[64*64];
  __shared__ bf16_t sBh[128*64], sBl[128*64];
  __shared__ float sS[64*128];
  int b = blockIdx.x;
  int tid = threadIdx.x, lane = tid&63, w = tid>>6;
  int wr = w>>1, wcc = w&1;
  f32x4 acc[2][4] = {};
  for (int kt=0; kt<1024; kt+=64){
    __syncthreads();
    #pragma unroll
    for (int i=0;i<2;i++){
      int c = i*256+tid; int r = c>>3, kk=(c&7)<<3;
      size_t src = (size_t)(r+1)*131072 + (size_t)b*1024 + kt+kk;
      gll16(h1h + src, sAh + (size_t)(i*256 + w*64)*8);
      gll16(h1l + src, sAl + (size_t)(i*256 + w*64)*8);
    }
    #pragma unroll
    for (int i=0;i<4;i++){
      int c = i*256+tid; int br=c>>3, kk=(c&7)<<3;
      size_t src = ((size_t)b*128 + br)*1024 + kt+kk;
      gll16(cwh + src, sBh + (size_t)(i*256+w*64)*8);
      gll16(cwl + src, sBl + (size_t)(i*256+w*64)*8);
    }
    __syncthreads();
    #pragma unroll
    for (int kk=0;kk<64;kk+=32){
      bf16x8 avh[2], avl[2], bvh[4], bvl[4];
      #pragma unroll
      for (int m=0;m<2;m++){
        int off = (wr*32 + m*16 + (lane&15))*64 + kk + ((lane>>4)<<3);
        avh[m] = *(const bf16x8*)(sAh + off);
        avl[m] = *(const bf16x8*)(sAl + off);
      }
      #pragma unroll
      for (int n=0;n<4;n++){
        int off = (wcc*64 + n*16 + (lane&15))*64 + kk + ((lane>>4)<<3);
        bvh[n] = *(const bf16x8*)(sBh + off);
        bvl[n] = *(const bf16x8*)(sBl + off);
      }
      #pragma unroll
      for (int m=0;m<2;m++)
        #pragma unroll
        for (int n=0;n<4;n++){
          acc[m][n] = __builtin_amdgcn_mfma_f32_16x16x32_bf16(avh[m], bvh[n], acc[m][n], 0,0,0);
          acc[m][n] = __builtin_amdgcn_mfma_f32_16x16x32_bf16(avl[m], bvh[n], acc[m][n], 0,0,0);
          acc[m][n] = __builtin_amdgcn_mfma_f32_16x16x32_bf16(avh[m], bvl[n], acc[m][n], 0,0,0);
        }
    }
  }
  #pragma unroll
  for (int m=0;m<2;m++)
    #pragma unroll
    for (int n=0;n<4;n++)
      #pragma unroll
      for (int r=0;r<4;r++){
        int trow = wr*32 + m*16 + ((lane>>4)<<2) + r;
        int tc   = wcc*64 + n*16 + (lane&15);
        sS[trow*128+tc] = acc[m][n][r];
      }
  __syncthreads();
  for (int i=0;i<16;i++){
    int r = w*16 + i;
    float v0 = sS[r*128 + lane], v1 = sS[r*128 + 64 + lane];
    float mx = fmaxf(v0, v1);
    #pragma unroll
    for (int off=32; off; off>>=1) mx = fmaxf(mx, __shfl_xor(mx, off));
    float e0 = expf(v0-mx), e1 = expf(v1-mx);
    float sm = e0+e1;
    #pragma unroll
    for (int off=32; off; off>>=1) sm += __shfl_xor(sm, off);
    float inv = 1.f/sm;
    size_t base = ((size_t)r*128 + b)*128;
    a_all[base + lane]      = e0*inv;
    a_all[base + 64 + lane] = e1*inv;
    if (r == 63){
      outA[(size_t)b*128 + lane]      = e0*inv;
      outA[(size_t)b*128 + 64 + lane] = e1*inv;
    }
  }
}

// ---------------- wc (fp32 VALU): wc[t,b,:] = sum_s a[t,b,s]*ctx[b,s,:] ----
__global__ __launch_bounds__(256) void wc_all(
    const float* __restrict__ a_all, const float* __restrict__ ctx,
    bf16_t* __restrict__ wch, bf16_t* __restrict__ wcl)
{
  int bid = blockIdx.x;
  int b = bid & 127, tg = bid >> 7;  // tg 0..3, 16 t each
  int tid = threadIdx.x;
  __shared__ float sa[16][128];
  int t0 = tg*16;
  #pragma unroll
  for (int i=0;i<8;i++){
    int q = i*256 + tid;
    int ti = q >> 7, s = q & 127;
    sa[ti][s] = a_all[((size_t)(t0+ti)*128 + b)*128 + s];
  }
  __syncthreads();
  f32x4 acc[16];
  #pragma unroll
  for (int i=0;i<16;i++) acc[i] = f32x4{0,0,0,0};
  const float* cb = ctx + (size_t)b*128*1024 + tid*4;
  for (int s=0;s<128;s++){
    f32x4 c = *(const f32x4*)(cb + (size_t)s*1024);
    #pragma unroll
    for (int ti=0;ti<16;ti++){
      float av = sa[ti][s];
      acc[ti] += av * c;
    }
  }
  #pragma unroll
  for (int ti=0;ti<16;ti++){
    size_t m = (size_t)(t0+ti)*128 + b;
    bf16x4 h, l;
    #pragma unroll
    for (int j=0;j<4;j++){
      float v = acc[ti][j];
      h[j] = (bf16_t)v; l[j] = (bf16_t)(v - (float)h[j]);
    }
    *(bf16x4*)(wch + m*1024 + tid*4) = h;
    *(bf16x4*)(wcl + m*1024 + tid*4) = l;
  }
}

// ---------------- host ----------------
extern "C" void kernel_launch(void* const* d_in, const int* in_sizes, int n_in,
                              void* d_out, int out_size, void* d_ws, size_t ws_size,
                              hipStream_t stream)
{
  (void)in_sizes; (void)n_in; (void)out_size; (void)ws_size;
  const int TT=64, BB=128, H=1024, G=4096, BH=128*1024;

  const int*   tok  = (const int*)d_in[0];
  const float* h0   = (const float*)d_in[1];
  const float* c0   = (const float*)d_in[2];
  const float* ctx  = (const float*)d_in[3];
  const float* embW = (const float*)d_in[5];
  const float* wih  = (const float*)d_in[6];
  const float* whh  = (const float*)d_in[7];
  const float* bih  = (const float*)d_in[8];
  const float* bhh  = (const float*)d_in[9];
  const float* Win  = (const float*)d_in[10];
  const float* Wout = (const float*)d_in[11];

  float* outY = (float*)d_out;                      // [T,B,H]
  float* outH = outY + (size_t)TT*BB*H;             // [2,B,H]
  float* outC = outH + (size_t)2*BH;                // [2,B,H]
  float* outA = outC + (size_t)2*BH;                // [B,S]

  char* ws = (char*)d_ws;
  size_t o = 0;
  auto carve = [&](size_t bytes)->char* {
    char* p = ws + o; o += (bytes + 255) & ~(size_t)255; return p;
  };
  bf16_t* wihB  = (bf16_t*)carve((size_t)2*G*H*2);       // 16MB
  bf16_t* whhB  = (bf16_t*)carve((size_t)2*G*H*2);       // 16MB
  bf16_t* woutH = (bf16_t*)carve((size_t)H*2*H*2);       // 4MB
  bf16_t* woutL = (bf16_t*)carve((size_t)H*2*H*2);       // 4MB
  bf16_t* winTh = (bf16_t*)carve((size_t)H*H*2);         // 2MB
  bf16_t* winTl = (bf16_t*)carve((size_t)H*H*2);         // 2MB
  bf16_t* ctxh  = (bf16_t*)carve((size_t)BB*128*H*2);    // 32MB; loop: h0 hist hi; post: wch
  bf16_t* ctxl  = (bf16_t*)carve((size_t)BB*128*H*2);    // 32MB; loop: h0 hist lo; post: wcl
  bf16_t* cwh   = (bf16_t*)carve((size_t)BB*128*H*2);    // 32MB (pre: xemb overlays)
  bf16_t* cwl   = (bf16_t*)carve((size_t)BB*128*H*2);    // 32MB
  bf16_t* x0gT  = (bf16_t*)carve((size_t)TT*BB*G*2);     // 64MB
  bf16_t* h1h   = (bf16_t*)carve((size_t)(TT+1)*BH*2);   // 17MB history
  bf16_t* h1l   = (bf16_t*)carve((size_t)(TT+1)*BH*2);   // 17MB
  float*  a_all = (float*)carve((size_t)TT*BB*128*4);    // 4MB
  float*  biasF = (float*)carve((size_t)2*G*4);
  int*    bar   = (int*)carve(16*64*4);

  bf16_t* xemb   = cwh;          // overlays ctxW-hi (dead until ctxW GEMM)
  bf16_t* h0hist = ctxh;         // h0 history [65][128][1024] (ctx dead after ctxW GEMM)
  bf16_t* h0histl= ctxl;
  bf16_t* wch    = ctxh;         // post-loop overlay (h0 hist dead then)
  bf16_t* wcl    = ctxl;

  // ---- prep ----
  hipMemsetAsync(bar, 0, 16*64*4, stream);
  f2b<<<(2*G*H)/1024, 256, 0, stream>>>(wih, wihB, 2*G*H);
  f2b<<<(2*G*H)/1024, 256, 0, stream>>>(whh, whhB, 2*G*H);
  f2b_pair<<<(H*2*H)/1024, 256, 0, stream>>>(Wout, woutH, woutL, H*2*H);
  f2b_pair<<<(BB*128*H)/1024, 256, 0, stream>>>(ctx, ctxh, ctxl, BB*128*H);
  f2b_pair<<<BH/1024, 256, 0, stream>>>(h0 + BH, h1h, h1l, BH);
  transWin<<<1024, 256, 0, stream>>>(Win, winTh, winTl);
  bias_combine<<<(2*G)/256, 256, 0, stream>>>(bih, bhh, biasF, 2*G);
  embed_gather<<<TT*BB, 256, 0, stream>>>(tok, embW, xemb);

  // ---- one-time GEMMs ----
  gemm_bt<<<(TT*BB/128)*(G/128), 256, 0, stream>>>(xemb, wihB, biasF, x0gT, TT*BB, G, H, G/128);
  gemm_split<0,1><<<(BB*128/128)*(H/128), 256, 0, stream>>>(
      ctxh, ctxl, ctxh, ctxl, H, winTh, winTl,
      nullptr, cwh + 0, cwl + 0, BB*128, H, H, H/128);
  // NOTE: gemm_split above writes cwh/cwl (the xemb region is dead after gemm_bt).

  // h0 layer-0 initial state -> h0 history slot 0 (ctx region now dead)
  f2b_pair<<<BH/1024, 256, 0, stream>>>(h0, h0hist, h0histl, BH);

  // ---- persistent recurrence ----
  hipFuncSetAttribute((const void*)lstm_loop,
                      hipFuncAttributeMaxDynamicSharedMemorySize, LDS_BYTES);
  lstm_loop<<<NBLK, 512, LDS_BYTES, stream>>>(
      whhB, wihB + (size_t)G*H, whhB + (size_t)G*H, x0gT, biasF + G, c0,
      h0hist, h0histl, h1h, h1l, outH, outC, bar);

  // ---- post-loop attention ----
  attn_sm<<<BB, 256, 0, stream>>>(h1h, h1l, cwh, cwl, a_all, outA);
  wc_all<<<BB*4, 256, 0, stream>>>(a_all, ctx, wch, wcl);

  gemm_split<1,0><<<(TT*BB/128)*(H/128), 256, 0, stream>>>(
      wch, wcl, h1h + BH, h1l + BH, H, woutH, woutL,
      outY, nullptr, nullptr, TT*BB, H, 2*H, H/128);
}